// Round 11
// baseline (546.797 us; speedup 1.0000x reference)
//
#include <hip/hip_runtime.h>
#include <hip/hip_bf16.h>
#include <cstddef>
#include <cstdint>

#define N_NODESC 100000
#define N_EDGESC 500000
#define NBATCH   512
#define SCAN_CHUNK 1024
#define CONV_KSPLIT 16
#define CONV_KCHUNK 384    // multiple of 32 -> k-octets stay channel-aligned; last split ragged (240)

static inline int divup(int a, int b) { return (a + b - 1) / b; }

typedef __hip_bfloat16 bf16;
typedef short s16x8 __attribute__((ext_vector_type(8)));
typedef float f32x4 __attribute__((ext_vector_type(4)));

__device__ inline float b2f(ushort u) {
    union { uint i; float f; } c; c.i = (uint)u << 16; return c.f;
}
__device__ inline ushort f2bs(float v) {
    bf16 b = __float2bfloat16(v);
    return *reinterpret_cast<ushort*>(&b);
}
__device__ inline void unpack2(uint u, float& a, float& b) {
    union { uint i; float f; } lo, hi;
    lo.i = u << 16; hi.i = u & 0xffff0000u;
    a = lo.f; b = hi.f;
}

// ---------------- zero ints ----------------
__global__ void zero_ints(int* __restrict__ p, int n) {
    int i = blockIdx.x * blockDim.x + threadIdx.x;
    if (i < n) p[i] = 0;
}

// ---------------- degree / dinv ----------------
__global__ void count_deg(const int* __restrict__ dst, int* __restrict__ deg, int e) {
    int i = blockIdx.x * blockDim.x + threadIdx.x;
    if (i < e) atomicAdd(&deg[dst[i]], 1);
}

__global__ void compute_dinv(const int* __restrict__ deg, float* __restrict__ dinv, int n) {
    int i = blockIdx.x * blockDim.x + threadIdx.x;
    if (i < n) dinv[i] = 1.0f / sqrtf((float)deg[i] + 1.0f);
}

// ---------------- exclusive scan (3-phase) ----------------
__global__ void scan_chunks(const int* __restrict__ deg, int* __restrict__ out,
                            int* __restrict__ sums, int n) {
    __shared__ int sdata[256];
    int t = threadIdx.x;
    int base = blockIdx.x * SCAN_CHUNK;
    int v[4];
    int s = 0;
#pragma unroll
    for (int j = 0; j < 4; ++j) {
        int idx = base + t * 4 + j;
        v[j] = s;
        int d = (idx < n) ? deg[idx] : 0;
        s += d;
    }
    int x = s;
    sdata[t] = x;
    __syncthreads();
    for (int off = 1; off < 256; off <<= 1) {
        int y = (t >= off) ? sdata[t - off] : 0;
        __syncthreads();
        x += y;
        sdata[t] = x;
        __syncthreads();
    }
    int thread_excl = x - s;
    if (t == 255) sums[blockIdx.x] = x;
#pragma unroll
    for (int j = 0; j < 4; ++j) {
        int idx = base + t * 4 + j;
        if (idx < n) out[idx] = thread_excl + v[j];
    }
}

__global__ void scan_sums(int* sums, int nchunks) {
    if (threadIdx.x == 0 && blockIdx.x == 0) {
        int acc = 0;
        for (int i = 0; i < nchunks; ++i) { int v = sums[i]; sums[i] = acc; acc += v; }
    }
}

__global__ void finalize_rowptr(int* __restrict__ row_ptr, const int* __restrict__ sums,
                                int* __restrict__ fill, int n, int e) {
    int i = blockIdx.x * blockDim.x + threadIdx.x;
    if (i < n) {
        int v = row_ptr[i] + sums[i / SCAN_CHUNK];
        row_ptr[i] = v;
        fill[i] = v;
    }
    if (i == 0) row_ptr[n] = e;
}

__global__ void fill_csr(const int* __restrict__ src, const int* __restrict__ dst,
                         int* __restrict__ fill, int* __restrict__ csr_src, int e) {
    int i = blockIdx.x * blockDim.x + threadIdx.x;
    if (i < e) {
        int d = dst[i];
        int pos = atomicAdd(&fill[d], 1);
        csr_src[pos] = src[i];
    }
}

// ---------------- batch segment pointers (batch is sorted) ----------------
__global__ void build_batch_ptr(const int* __restrict__ batch, int* __restrict__ bptr,
                                int n, int nb) {
    int i = blockIdx.x * blockDim.x + threadIdx.x;
    if (i >= n) return;
    int b = batch[i];
    int prev = (i == 0) ? -1 : batch[i - 1];
    for (int bb = prev + 1; bb <= b; ++bb) bptr[bb] = i;
    if (i == n - 1) {
        for (int bb = b + 1; bb <= nb; ++bb) bptr[bb] = n;
    }
}

// ---------------- fp32 -> bf16 node-feature conversion with padded stride ----------------
__global__ void convert_x_bf16(const float* __restrict__ x, ushort* __restrict__ xbf,
                               int n, int ki, int ld) {
    int i = blockIdx.x * blockDim.x + threadIdx.x;
    int total = n * ld;
    if (i >= total) return;
    int node = i / ld, col = i % ld;
    xbf[i] = (col < ki) ? f2bs(x[(size_t)node * ki + col]) : (ushort)0;
}

// ---------------- W[KI,KO] fp32 -> Wt[KO,LD] bf16 (transposed, zero-padded) ----------------
__global__ void transpose_w_bf16(const float* __restrict__ W, ushort* __restrict__ Wt,
                                 int ki, int ko, int ld) {
    int i = blockIdx.x * blockDim.x + threadIdx.x;
    int total = ko * ld;
    if (i >= total) return;
    int o = i / ld, k = i % ld;
    Wt[i] = (k < ki) ? f2bs(W[(size_t)k * ko + o]) : (ushort)0;
}

// ---------------- Kxt[32][6000] fp32 -> Kbf[32][6016] bf16 (zero-padded) ----------------
__global__ void convert_k_bf16(const float* __restrict__ Kxt, ushort* __restrict__ Kbf) {
    int i = blockIdx.x * blockDim.x + threadIdx.x;
    if (i >= 32 * 6016) return;
    int o = i / 6016, k = i % 6016;
    Kbf[i] = (k < 6000) ? f2bs(Kxt[(size_t)o * 6000 + k]) : (ushort)0;
}

// ---------------- vectorized GCN aggregation: agg = \hat{A} h ----------------
template <int LD>
__global__ void gcn_gather_vec(const ushort* __restrict__ h, const int* __restrict__ row_ptr,
                               const int* __restrict__ csr_src, const float* __restrict__ dinv,
                               ushort* __restrict__ agg, int n) {
    constexpr int TPN = LD / 8;
    int gid = blockIdx.x * blockDim.x + threadIdx.x;
    int node = gid / TPN, oct = gid % TPN;
    if (node >= n) return;
    float dn = dinv[node];
    int e0 = row_ptr[node], e1 = row_ptr[node + 1];
    float acc[8];
    {   // self loop: dinv^2 * h[node]
        uint4 v = *reinterpret_cast<const uint4*>(&h[(size_t)node * LD + oct * 8]);
        float w = dn * dn;
        float a, b;
        unpack2(v.x, a, b); acc[0] = a * w; acc[1] = b * w;
        unpack2(v.y, a, b); acc[2] = a * w; acc[3] = b * w;
        unpack2(v.z, a, b); acc[4] = a * w; acc[5] = b * w;
        unpack2(v.w, a, b); acc[6] = a * w; acc[7] = b * w;
    }
    for (int e = e0; e < e1; ++e) {
        int s = csr_src[e];
        float w = dinv[s] * dn;
        uint4 v = *reinterpret_cast<const uint4*>(&h[(size_t)s * LD + oct * 8]);
        float a, b;
        unpack2(v.x, a, b); acc[0] = fmaf(a, w, acc[0]); acc[1] = fmaf(b, w, acc[1]);
        unpack2(v.y, a, b); acc[2] = fmaf(a, w, acc[2]); acc[3] = fmaf(b, w, acc[3]);
        unpack2(v.z, a, b); acc[4] = fmaf(a, w, acc[4]); acc[5] = fmaf(b, w, acc[5]);
        unpack2(v.w, a, b); acc[6] = fmaf(a, w, acc[6]); acc[7] = fmaf(b, w, acc[7]);
    }
    uint4 o;
    o.x = (uint)f2bs(acc[0]) | ((uint)f2bs(acc[1]) << 16);
    o.y = (uint)f2bs(acc[2]) | ((uint)f2bs(acc[3]) << 16);
    o.z = (uint)f2bs(acc[4]) | ((uint)f2bs(acc[5]) << 16);
    o.w = (uint)f2bs(acc[6]) | ((uint)f2bs(acc[7]) << 16);
    *reinterpret_cast<uint4*>(&agg[(size_t)node * LD + oct * 8]) = o;
}

// ---------------- bf16 MFMA GEMM: C = A @ Wt^T (+bias)(+relu), bf16 out ----------------
template <int KI, int LDA, int KO, int LDC, bool BIASRELU>
__global__ __launch_bounds__(256) void gemm_mfma(const ushort* __restrict__ A,
                                                 const ushort* __restrict__ Bt,
                                                 const float* __restrict__ bias,
                                                 ushort* __restrict__ C, int n) {
    __shared__ ushort sA[64][40];
    __shared__ ushort sB[64][40];
    const int t = threadIdx.x;
    const int row0 = blockIdx.x * 64;
    const int col0 = blockIdx.y * 64;
    const int wid = t >> 6, lane = t & 63;
    const int wr = wid >> 1, wc = wid & 1;
    const int lrow = lane & 15;
    const int kgrp = lane >> 4;
    const int srr = t >> 2;      // staging row 0..63
    const int skq = t & 3;       // staging k-octet
    f32x4 acc[2][2];
#pragma unroll
    for (int i = 0; i < 2; ++i)
#pragma unroll
        for (int j = 0; j < 2; ++j) acc[i][j] = (f32x4)0.f;

    const int nk = (KI + 31) / 32;
    for (int ks = 0; ks < nk; ++ks) {
        const int kbase = ks * 32 + skq * 8;
        {   // stage A tile (64 rows x 32 k)
            int grow = row0 + srr;
            uint4 v = {0, 0, 0, 0};
            if (grow < n && kbase < LDA)
                v = *reinterpret_cast<const uint4*>(&A[(size_t)grow * LDA + kbase]);
            *reinterpret_cast<uint4*>(&sA[srr][skq * 8]) = v;
        }
        {   // stage B tile (64 cols x 32 k)
            int gcol = col0 + srr;
            uint4 v = {0, 0, 0, 0};
            if (gcol < KO && kbase < LDA)
                v = *reinterpret_cast<const uint4*>(&Bt[(size_t)gcol * LDA + kbase]);
            *reinterpret_cast<uint4*>(&sB[srr][skq * 8]) = v;
        }
        __syncthreads();
        s16x8 a0 = *reinterpret_cast<const s16x8*>(&sA[wr * 32 + lrow][kgrp * 8]);
        s16x8 a1 = *reinterpret_cast<const s16x8*>(&sA[wr * 32 + 16 + lrow][kgrp * 8]);
        s16x8 b0 = *reinterpret_cast<const s16x8*>(&sB[wc * 32 + lrow][kgrp * 8]);
        s16x8 b1 = *reinterpret_cast<const s16x8*>(&sB[wc * 32 + 16 + lrow][kgrp * 8]);
        acc[0][0] = __builtin_amdgcn_mfma_f32_16x16x32_bf16(a0, b0, acc[0][0], 0, 0, 0);
        acc[0][1] = __builtin_amdgcn_mfma_f32_16x16x32_bf16(a0, b1, acc[0][1], 0, 0, 0);
        acc[1][0] = __builtin_amdgcn_mfma_f32_16x16x32_bf16(a1, b0, acc[1][0], 0, 0, 0);
        acc[1][1] = __builtin_amdgcn_mfma_f32_16x16x32_bf16(a1, b1, acc[1][1], 0, 0, 0);
        __syncthreads();
    }
#pragma unroll
    for (int fr = 0; fr < 2; ++fr)
#pragma unroll
        for (int fc = 0; fc < 2; ++fc)
#pragma unroll
            for (int r = 0; r < 4; ++r) {
                int row = row0 + wr * 32 + fr * 16 + kgrp * 4 + r;
                int col = col0 + wc * 32 + fc * 16 + lrow;
                if (row < n && col < LDC) {
                    float v = acc[fr][fc][r];
                    ushort o = 0;
                    if (col < KO) {
                        if (BIASRELU) v = fmaxf(v + bias[col], 0.f);
                        o = f2bs(v);
                    }
                    C[(size_t)row * LDC + col] = o;
                }
            }
}

// ---------------- segment max pool, vectorized (thread = batch x col-octet) ----------------
__global__ void seg_max_vec(const ushort* __restrict__ h, const int* __restrict__ bptr,
                            float* __restrict__ g) {
    int gid = blockIdx.x * blockDim.x + threadIdx.x;
    int b = gid / 39, oct = gid - b * 39;   // 312 = 39 octets
    if (b >= NBATCH) return;
    int n0 = bptr[b], n1 = bptr[b + 1];
    float m[8];
#pragma unroll
    for (int j = 0; j < 8; ++j) m[j] = -INFINITY;
    for (int n = n0; n < n1; ++n) {
        uint4 v = *reinterpret_cast<const uint4*>(&h[(size_t)n * 312 + oct * 8]);
        float a, c;
        unpack2(v.x, a, c); m[0] = fmaxf(m[0], a); m[1] = fmaxf(m[1], c);
        unpack2(v.y, a, c); m[2] = fmaxf(m[2], a); m[3] = fmaxf(m[3], c);
        unpack2(v.z, a, c); m[4] = fmaxf(m[4], a); m[5] = fmaxf(m[5], c);
        unpack2(v.w, a, c); m[6] = fmaxf(m[6], a); m[7] = fmaxf(m[7], c);
    }
#pragma unroll
    for (int j = 0; j < 8; ++j) g[(size_t)b * 312 + oct * 8 + j] = m[j];
}

// ---------------- head GEMM: K-split, 32x64 tile, fp32 partials ----------------
template <int KI, int KO, int KS>
__global__ __launch_bounds__(256) void gemm_head(const float* __restrict__ A,
                                                 const float* __restrict__ W,
                                                 float* __restrict__ partial, int n) {
    __shared__ float sA[16][34];
    __shared__ float sW[16][68];
    const int t = threadIdx.x;
    const int row0 = blockIdx.x * 32;
    const int col0 = blockIdx.y * 64;
    const int z = blockIdx.z;
    const int kbeg = z * KS;
    const int kend = min(KI, kbeg + KS);
    const int r0 = (t >> 4) * 2;   // 0..30 (even)
    const int c0 = (t & 15) * 4;   // 0..60 (quad)
    float acc[2][4] = {};
    for (int k0 = kbeg; k0 < kend; k0 += 16) {
        {   // stage A: 32 rows x 16 k
            int row = t >> 3, kk = (t & 7) * 2;
            int grow = row0 + row;
#pragma unroll
            for (int j = 0; j < 2; ++j) {
                float v = 0.f;
                if (grow < n && (k0 + kk + j) < kend) v = A[(size_t)grow * KI + k0 + kk + j];
                sA[kk + j][row] = v;
            }
        }
        {   // stage W: 16 k x 64 cols
            int kk = t >> 4, cc = (t & 15) * 4;
#pragma unroll
            for (int j = 0; j < 4; ++j) {
                float v = 0.f;
                if ((k0 + kk) < kend) v = W[(size_t)(k0 + kk) * KO + col0 + cc + j];
                sW[kk][cc + j] = v;
            }
        }
        __syncthreads();
#pragma unroll 8
        for (int k = 0; k < 16; ++k) {
            float2 a = *reinterpret_cast<const float2*>(&sA[k][r0]);
            float4 w = *reinterpret_cast<const float4*>(&sW[k][c0]);
            acc[0][0] = fmaf(a.x, w.x, acc[0][0]); acc[0][1] = fmaf(a.x, w.y, acc[0][1]);
            acc[0][2] = fmaf(a.x, w.z, acc[0][2]); acc[0][3] = fmaf(a.x, w.w, acc[0][3]);
            acc[1][0] = fmaf(a.y, w.x, acc[1][0]); acc[1][1] = fmaf(a.y, w.y, acc[1][1]);
            acc[1][2] = fmaf(a.y, w.z, acc[1][2]); acc[1][3] = fmaf(a.y, w.w, acc[1][3]);
        }
        __syncthreads();
    }
#pragma unroll
    for (int ri = 0; ri < 2; ++ri) {
        int row = row0 + r0 + ri;
        if (row >= n) continue;
        *reinterpret_cast<float4*>(&partial[((size_t)z * n + row) * KO + col0 + c0]) =
            make_float4(acc[ri][0], acc[ri][1], acc[ri][2], acc[ri][3]);
    }
}

// sum partials over splits + bias (+relu), scatter into C[row*ldc + col_off + col]
template <int NS, bool RELU>
__global__ void head_reduce(const float* __restrict__ partial, const float* __restrict__ bias,
                            float* __restrict__ C, int n, int KO, int ldc, int col_off) {
    int j = blockIdx.x * blockDim.x + threadIdx.x;
    if (j >= n * KO) return;
    int row = j / KO, col = j % KO;
    float acc = bias[col];
#pragma unroll
    for (int s = 0; s < NS; ++s) acc += partial[((size_t)s * n + row) * KO + col];
    if (RELU) acc = fmaxf(acc, 0.f);
    C[(size_t)row * ldc + col_off + col] = acc;
}

// ---------------- Conv1d as implicit GEMM via MFMA (bf16), K-split ----------------
// C[6144,32] = A[6144,6000] @ B[6000,32]; A[(b*12+h)][i*8+kh] = T[b,i,h+kh]; B[k][o] = Kxt[o,k].
// A staged fp32->bf16 in-register; B from pre-converted Kbf[32][6016] (zero-padded).
// 4 waves: wave w computes rows [16w,16w+16) x all 32 cols (2 MFMA per K32-step).
__global__ __launch_bounds__(256) void conv_mfma(const float* __restrict__ T,
                                                 const ushort* __restrict__ Kbf,
                                                 float* __restrict__ partial) {
    __shared__ ushort sA[64][40];
    __shared__ ushort sB[32][40];
    const int t = threadIdx.x;
    const int row0 = blockIdx.x * 64;
    const int split = blockIdx.y;
    const int kbeg = split * CONV_KCHUNK;
    const int kend = min(6000, kbeg + CONV_KCHUNK);
    const int wid = t >> 6, lane = t & 63;
    const int lrow = lane & 15, kgrp = lane >> 4;
    f32x4 acc0 = (f32x4)0.f, acc1 = (f32x4)0.f;
    for (int k0 = kbeg; k0 < kend; k0 += 32) {
        {   // stage A (64 rows x 32 k): load fp32 T, convert to bf16 (kb multiple of 8)
            int rr = t >> 2, kq = t & 3;
            int grow = row0 + rr;                 // < 6144 always
            int b = grow / 12, h = grow % 12;
            int kb = k0 + kq * 8;
            int i = kb >> 3;
            const float* tp = &T[(size_t)b * 14250 + (size_t)i * 19 + h];
            ushort u[8];
#pragma unroll
            for (int j = 0; j < 8; ++j)
                u[j] = (kb + j < kend) ? f2bs(tp[j]) : (ushort)0;
            uint4 v;
            v.x = (uint)u[0] | ((uint)u[1] << 16);
            v.y = (uint)u[2] | ((uint)u[3] << 16);
            v.z = (uint)u[4] | ((uint)u[5] << 16);
            v.w = (uint)u[6] | ((uint)u[7] << 16);
            *reinterpret_cast<uint4*>(&sA[rr][kq * 8]) = v;
        }
        if (t < 128) {   // stage B (32 outs x 32 k) from padded Kbf (pad -> A zeros anyway)
            int o = t >> 2, kq = t & 3;
            uint4 v = *reinterpret_cast<const uint4*>(&Kbf[(size_t)o * 6016 + k0 + kq * 8]);
            *reinterpret_cast<uint4*>(&sB[o][kq * 8]) = v;
        }
        __syncthreads();
        s16x8 a0 = *reinterpret_cast<const s16x8*>(&sA[wid * 16 + lrow][kgrp * 8]);
        s16x8 b0 = *reinterpret_cast<const s16x8*>(&sB[lrow][kgrp * 8]);
        s16x8 b1 = *reinterpret_cast<const s16x8*>(&sB[16 + lrow][kgrp * 8]);
        acc0 = __builtin_amdgcn_mfma_f32_16x16x32_bf16(a0, b0, acc0, 0, 0, 0);
        acc1 = __builtin_amdgcn_mfma_f32_16x16x32_bf16(a0, b1, acc1, 0, 0, 0);
        __syncthreads();
    }
#pragma unroll
    for (int r = 0; r < 4; ++r) {
        int row = row0 + wid * 16 + kgrp * 4 + r;   // C/D: row=(lane>>4)*4+reg, col=lane&15
        int b = row / 12, h = row % 12;
        partial[(((size_t)split * NBATCH + b) * 32 + lrow) * 12 + h] = acc0[r];
        partial[(((size_t)split * NBATCH + b) * 32 + (16 + lrow)) * 12 + h] = acc1[r];
    }
}

__global__ void conv_reduce(const float* __restrict__ partial, const float* __restrict__ bxt,
                            float* __restrict__ convb) {
    int j = blockIdx.x * blockDim.x + threadIdx.x;
    if (j >= NBATCH * 384) return;
    int b = j / 384, rem = j % 384;
    int o = rem / 12, h = rem % 12;
    float acc = bxt[o];
#pragma unroll
    for (int s = 0; s < CONV_KSPLIT; ++s)
        acc += partial[(((size_t)s * NBATCH + b) * 32 + o) * 12 + h];
    convb[j] = acc;
}

// ---------------- final [512,512] @ [512,1] ----------------
__global__ void final_out(const float* __restrict__ f2, const float* __restrict__ Wo,
                          const float* __restrict__ bo, float* __restrict__ out) {
    int row = blockIdx.x * (blockDim.x / 64) + (threadIdx.x / 64);
    int lane = threadIdx.x & 63;
    if (row >= NBATCH) return;
    float acc = 0.f;
    for (int k = lane; k < 512; k += 64) acc = fmaf(f2[(size_t)row * 512 + k], Wo[k], acc);
#pragma unroll
    for (int off = 32; off > 0; off >>= 1) acc += __shfl_down(acc, off);
    if (lane == 0) out[row] = acc + bo[0];
}

extern "C" void kernel_launch(void* const* d_in, const int* in_sizes, int n_in,
                              void* d_out, int out_size, void* d_ws, size_t ws_size,
                              hipStream_t stream) {
    (void)in_sizes; (void)n_in; (void)out_size; (void)ws_size;
    const float* x     = (const float*)d_in[0];
    const int*   ei    = (const int*)d_in[1];
    const int*   batch = (const int*)d_in[2];
    const float* T     = (const float*)d_in[3];
    const float* W1 = (const float*)d_in[4];   const float* b1 = (const float*)d_in[5];
    const float* W2 = (const float*)d_in[6];   const float* b2 = (const float*)d_in[7];
    const float* W3 = (const float*)d_in[8];   const float* b3 = (const float*)d_in[9];
    const float* Wg1 = (const float*)d_in[10]; const float* bg1 = (const float*)d_in[11];
    const float* Wg2 = (const float*)d_in[12]; const float* bg2 = (const float*)d_in[13];
    const float* Kxt = (const float*)d_in[14]; const float* bxt = (const float*)d_in[15];
    const float* Wxt = (const float*)d_in[16]; const float* bxt2 = (const float*)d_in[17];
    const float* Wf1 = (const float*)d_in[18]; const float* bf1 = (const float*)d_in[19];
    const float* Wf2 = (const float*)d_in[20]; const float* bf2 = (const float*)d_in[21];
    const float* Wo = (const float*)d_in[22];  const float* bo = (const float*)d_in[23];
    const int* src = ei;
    const int* dst = ei + N_EDGESC;

    char* ws = (char*)d_ws;
    size_t off = 0;
    auto alloc = [&](size_t bytes) -> void* {
        void* p = ws + off;
        off += (bytes + 255) & ~(size_t)255;
        return p;
    };
    // ~139 MB total
    int*   deg      = (int*)alloc((size_t)N_NODESC * 4);
    float* dinv     = (float*)alloc((size_t)N_NODESC * 4);
    int*   row_ptr  = (int*)alloc((size_t)(N_NODESC + 1) * 4);
    int*   fillc    = (int*)alloc((size_t)N_NODESC * 4);
    int*   csr_src  = (int*)alloc((size_t)N_EDGESC * 4);
    int*   csums    = (int*)alloc((size_t)4096 * 4);
    int*   bptr     = (int*)alloc((size_t)(NBATCH + 1) * 4);
    float* g0       = (float*)alloc((size_t)NBATCH * 312 * 4);
    float* g1       = (float*)alloc((size_t)NBATCH * 1024 * 4);
    float* convb    = (float*)alloc((size_t)NBATCH * 384 * 4);
    float* xc       = (float*)alloc((size_t)NBATCH * 256 * 4);
    float* f1       = (float*)alloc((size_t)NBATCH * 1024 * 4);
    float* f2       = (float*)alloc((size_t)NBATCH * 512 * 4);
    float* cpart    = (float*)alloc((size_t)CONV_KSPLIT * NBATCH * 32 * 12 * 4);
    float* hpart    = (float*)alloc((size_t)8 * NBATCH * 128 * 4);  // 2MB: all head splits fit
    ushort* xbf     = (ushort*)alloc((size_t)N_NODESC * 80 * 2);   // x (80) -> later h1 (80)
    ushort* aggbuf  = (ushort*)alloc((size_t)N_NODESC * 160 * 2);  // agg1/2 (80), agg3 (160)
    ushort* hbuf    = (ushort*)alloc((size_t)N_NODESC * 312 * 2);  // h2 (160), h3 (312)
    ushort* Wt1     = (ushort*)alloc((size_t)78 * 80 * 2);
    ushort* Wt2     = (ushort*)alloc((size_t)156 * 80 * 2);
    ushort* Wt3     = (ushort*)alloc((size_t)312 * 160 * 2);
    ushort* Kbf     = (ushort*)alloc((size_t)32 * 6016 * 2);
    float* out      = (float*)d_out;

    const int TPB = 256;

    // ---- graph structure ----
    zero_ints<<<divup(N_NODESC, TPB), TPB, 0, stream>>>(deg, N_NODESC);
    count_deg<<<divup(N_EDGESC, TPB), TPB, 0, stream>>>(dst, deg, N_EDGESC);
    compute_dinv<<<divup(N_NODESC, TPB), TPB, 0, stream>>>(deg, dinv, N_NODESC);
    int nchunks = divup(N_NODESC, SCAN_CHUNK);
    scan_chunks<<<nchunks, 256, 0, stream>>>(deg, row_ptr, csums, N_NODESC);
    scan_sums<<<1, 64, 0, stream>>>(csums, nchunks);
    finalize_rowptr<<<divup(N_NODESC, TPB), TPB, 0, stream>>>(row_ptr, csums, fillc, N_NODESC, N_EDGESC);
    fill_csr<<<divup(N_EDGESC, TPB), TPB, 0, stream>>>(src, dst, fillc, csr_src, N_EDGESC);
    build_batch_ptr<<<divup(N_NODESC, TPB), TPB, 0, stream>>>(batch, bptr, N_NODESC, NBATCH);

    // ---- bf16 conversions ----
    convert_x_bf16<<<divup(N_NODESC * 80, TPB), TPB, 0, stream>>>(x, xbf, N_NODESC, 78, 80);
    transpose_w_bf16<<<divup(78 * 80, TPB), TPB, 0, stream>>>(W1, Wt1, 78, 78, 80);
    transpose_w_bf16<<<divup(156 * 80, TPB), TPB, 0, stream>>>(W2, Wt2, 78, 156, 80);
    transpose_w_bf16<<<divup(312 * 160, TPB), TPB, 0, stream>>>(W3, Wt3, 156, 312, 160);
    convert_k_bf16<<<divup(32 * 6016, TPB), TPB, 0, stream>>>(Kxt, Kbf);

    // ---- GCN layer 1: agg(x) -> gemm+bias+relu -> h1 (LD 80) ----
    gcn_gather_vec<80><<<divup(N_NODESC * 10, TPB), TPB, 0, stream>>>(
        xbf, row_ptr, csr_src, dinv, aggbuf, N_NODESC);
    gemm_mfma<78, 80, 78, 80, true><<<dim3(divup(N_NODESC, 64), 2), 256, 0, stream>>>(
        aggbuf, Wt1, b1, xbf, N_NODESC);   // h1 overwrites xbf (x dead)

    // ---- GCN layer 2: agg(h1) -> gemm -> h2 (LD 160) ----
    gcn_gather_vec<80><<<divup(N_NODESC * 10, TPB), TPB, 0, stream>>>(
        xbf, row_ptr, csr_src, dinv, aggbuf, N_NODESC);
    gemm_mfma<78, 80, 156, 160, true><<<dim3(divup(N_NODESC, 64), 3), 256, 0, stream>>>(
        aggbuf, Wt2, b2, hbuf, N_NODESC);

    // ---- GCN layer 3: agg(h2) -> gemm -> h3 (LD 312) ----
    gcn_gather_vec<160><<<divup(N_NODESC * 20, TPB), TPB, 0, stream>>>(
        hbuf, row_ptr, csr_src, dinv, aggbuf, N_NODESC);
    gemm_mfma<156, 160, 312, 312, true><<<dim3(divup(N_NODESC, 64), 5), 256, 0, stream>>>(
        aggbuf, Wt3, b3, hbuf, N_NODESC);

    // ---- global max pool ----
    seg_max_vec<<<divup(NBATCH * 39, TPB), TPB, 0, stream>>>(hbuf, bptr, g0);

    // ---- graph head: g1 = relu(g0 @ Wg1 + bg1) ----
    gemm_head<312, 1024, 312><<<dim3(16, 16, 1), 256, 0, stream>>>(g0, Wg1, hpart, NBATCH);
    head_reduce<1, true><<<divup(NBATCH * 1024, TPB), TPB, 0, stream>>>(
        hpart, bg1, g1, NBATCH, 1024, 1024, 0);
    // xc[:, :128] = g1 @ Wg2 + bg2
    gemm_head<1024, 128, 128><<<dim3(16, 2, 8), 256, 0, stream>>>(g1, Wg2, hpart, NBATCH);
    head_reduce<8, false><<<divup(NBATCH * 128, TPB), TPB, 0, stream>>>(
        hpart, bg2, xc, NBATCH, 128, 256, 0);

    // ---- protein branch: implicit-GEMM conv via MFMA ----
    conv_mfma<<<dim3(6144 / 64, CONV_KSPLIT), 256, 0, stream>>>(T, Kbf, cpart);
    conv_reduce<<<divup(NBATCH * 384, TPB), TPB, 0, stream>>>(cpart, bxt, convb);
    // xc[:, 128:] = convb @ Wxt + bxt2
    gemm_head<384, 128, 48><<<dim3(16, 2, 8), 256, 0, stream>>>(convb, Wxt, hpart, NBATCH);
    head_reduce<8, false><<<divup(NBATCH * 128, TPB), TPB, 0, stream>>>(
        hpart, bxt2, xc, NBATCH, 128, 256, 128);

    // ---- fusion MLP ----
    gemm_head<256, 1024, 256><<<dim3(16, 16, 1), 256, 0, stream>>>(xc, Wf1, hpart, NBATCH);
    head_reduce<1, true><<<divup(NBATCH * 1024, TPB), TPB, 0, stream>>>(
        hpart, bf1, f1, NBATCH, 1024, 1024, 0);
    gemm_head<1024, 512, 512><<<dim3(16, 8, 2), 256, 0, stream>>>(f1, Wf2, hpart, NBATCH);
    head_reduce<2, true><<<divup(NBATCH * 512, TPB), TPB, 0, stream>>>(
        hpart, bf2, f2, NBATCH, 512, 512, 0);
    final_out<<<divup(NBATCH, 4), 256, 0, stream>>>(f2, Wo, bo, out);
}

// Round 12
// 505.759 us; speedup vs baseline: 1.0811x; 1.0811x over previous
//
#include <hip/hip_runtime.h>
#include <hip/hip_bf16.h>
#include <cstddef>
#include <cstdint>

#define N_NODESC 100000
#define N_EDGESC 500000
#define NBATCH   512
#define SCAN_CHUNK 1024
#define CONV_KSPLIT 16
#define CONV_KCHUNK 384    // multiple of 32 -> k-octets stay channel-aligned; last split ragged (240)

static inline int divup(int a, int b) { return (a + b - 1) / b; }

typedef __hip_bfloat16 bf16;
typedef short s16x8 __attribute__((ext_vector_type(8)));
typedef float f32x4 __attribute__((ext_vector_type(4)));

__device__ inline float b2f(ushort u) {
    union { uint i; float f; } c; c.i = (uint)u << 16; return c.f;
}
__device__ inline ushort f2bs(float v) {
    bf16 b = __float2bfloat16(v);
    return *reinterpret_cast<ushort*>(&b);
}
__device__ inline void unpack2(uint u, float& a, float& b) {
    union { uint i; float f; } lo, hi;
    lo.i = u << 16; hi.i = u & 0xffff0000u;
    a = lo.f; b = hi.f;
}

// ---------------- zero ints ----------------
__global__ void zero_ints(int* __restrict__ p, int n) {
    int i = blockIdx.x * blockDim.x + threadIdx.x;
    if (i < n) p[i] = 0;
}

// ---------------- degree / dinv ----------------
__global__ void count_deg(const int* __restrict__ dst, int* __restrict__ deg, int e) {
    int i = blockIdx.x * blockDim.x + threadIdx.x;
    if (i < e) atomicAdd(&deg[dst[i]], 1);
}

__global__ void compute_dinv(const int* __restrict__ deg, float* __restrict__ dinv, int n) {
    int i = blockIdx.x * blockDim.x + threadIdx.x;
    if (i < n) dinv[i] = 1.0f / sqrtf((float)deg[i] + 1.0f);
}

// ---------------- exclusive scan (3-phase) ----------------
__global__ void scan_chunks(const int* __restrict__ deg, int* __restrict__ out,
                            int* __restrict__ sums, int n) {
    __shared__ int sdata[256];
    int t = threadIdx.x;
    int base = blockIdx.x * SCAN_CHUNK;
    int v[4];
    int s = 0;
#pragma unroll
    for (int j = 0; j < 4; ++j) {
        int idx = base + t * 4 + j;
        v[j] = s;
        int d = (idx < n) ? deg[idx] : 0;
        s += d;
    }
    int x = s;
    sdata[t] = x;
    __syncthreads();
    for (int off = 1; off < 256; off <<= 1) {
        int y = (t >= off) ? sdata[t - off] : 0;
        __syncthreads();
        x += y;
        sdata[t] = x;
        __syncthreads();
    }
    int thread_excl = x - s;
    if (t == 255) sums[blockIdx.x] = x;
#pragma unroll
    for (int j = 0; j < 4; ++j) {
        int idx = base + t * 4 + j;
        if (idx < n) out[idx] = thread_excl + v[j];
    }
}

__global__ void scan_sums(int* sums, int nchunks) {
    if (threadIdx.x == 0 && blockIdx.x == 0) {
        int acc = 0;
        for (int i = 0; i < nchunks; ++i) { int v = sums[i]; sums[i] = acc; acc += v; }
    }
}

__global__ void finalize_rowptr(int* __restrict__ row_ptr, const int* __restrict__ sums,
                                int* __restrict__ fill, int n, int e) {
    int i = blockIdx.x * blockDim.x + threadIdx.x;
    if (i < n) {
        int v = row_ptr[i] + sums[i / SCAN_CHUNK];
        row_ptr[i] = v;
        fill[i] = v;
    }
    if (i == 0) row_ptr[n] = e;
}

__global__ void fill_csr(const int* __restrict__ src, const int* __restrict__ dst,
                         int* __restrict__ fill, int* __restrict__ csr_src, int e) {
    int i = blockIdx.x * blockDim.x + threadIdx.x;
    if (i < e) {
        int d = dst[i];
        int pos = atomicAdd(&fill[d], 1);
        csr_src[pos] = src[i];
    }
}

// ---------------- fp32 -> bf16 node-feature conversion with padded stride ----------------
__global__ void convert_x_bf16(const float* __restrict__ x, ushort* __restrict__ xbf,
                               int n, int ki, int ld) {
    int i = blockIdx.x * blockDim.x + threadIdx.x;
    int total = n * ld;
    if (i >= total) return;
    int node = i / ld, col = i % ld;
    xbf[i] = (col < ki) ? f2bs(x[(size_t)node * ki + col]) : (ushort)0;
}

// ---------------- W[KI,KO] fp32 -> Wt[KO,LD] bf16 (transposed, zero-padded) ----------------
__global__ void transpose_w_bf16(const float* __restrict__ W, ushort* __restrict__ Wt,
                                 int ki, int ko, int ld) {
    int i = blockIdx.x * blockDim.x + threadIdx.x;
    int total = ko * ld;
    if (i >= total) return;
    int o = i / ld, k = i % ld;
    Wt[i] = (k < ki) ? f2bs(W[(size_t)k * ko + o]) : (ushort)0;
}

// ---------------- Kxt[32][6000] fp32 -> Kbf[32][6016] bf16 (zero-padded) ----------------
__global__ void convert_k_bf16(const float* __restrict__ Kxt, ushort* __restrict__ Kbf) {
    int i = blockIdx.x * blockDim.x + threadIdx.x;
    if (i >= 32 * 6016) return;
    int o = i / 6016, k = i % 6016;
    Kbf[i] = (k < 6000) ? f2bs(Kxt[(size_t)o * 6000 + k]) : (ushort)0;
}

// ---------------- vectorized GCN aggregation: agg = \hat{A} h ----------------
template <int LD>
__global__ void gcn_gather_vec(const ushort* __restrict__ h, const int* __restrict__ row_ptr,
                               const int* __restrict__ csr_src, const float* __restrict__ dinv,
                               ushort* __restrict__ agg, int n) {
    constexpr int TPN = LD / 8;
    int gid = blockIdx.x * blockDim.x + threadIdx.x;
    int node = gid / TPN, oct = gid % TPN;
    if (node >= n) return;
    float dn = dinv[node];
    int e0 = row_ptr[node], e1 = row_ptr[node + 1];
    float acc[8];
    {   // self loop: dinv^2 * h[node]
        uint4 v = *reinterpret_cast<const uint4*>(&h[(size_t)node * LD + oct * 8]);
        float w = dn * dn;
        float a, b;
        unpack2(v.x, a, b); acc[0] = a * w; acc[1] = b * w;
        unpack2(v.y, a, b); acc[2] = a * w; acc[3] = b * w;
        unpack2(v.z, a, b); acc[4] = a * w; acc[5] = b * w;
        unpack2(v.w, a, b); acc[6] = a * w; acc[7] = b * w;
    }
    for (int e = e0; e < e1; ++e) {
        int s = csr_src[e];
        float w = dinv[s] * dn;
        uint4 v = *reinterpret_cast<const uint4*>(&h[(size_t)s * LD + oct * 8]);
        float a, b;
        unpack2(v.x, a, b); acc[0] = fmaf(a, w, acc[0]); acc[1] = fmaf(b, w, acc[1]);
        unpack2(v.y, a, b); acc[2] = fmaf(a, w, acc[2]); acc[3] = fmaf(b, w, acc[3]);
        unpack2(v.z, a, b); acc[4] = fmaf(a, w, acc[4]); acc[5] = fmaf(b, w, acc[5]);
        unpack2(v.w, a, b); acc[6] = fmaf(a, w, acc[6]); acc[7] = fmaf(b, w, acc[7]);
    }
    uint4 o;
    o.x = (uint)f2bs(acc[0]) | ((uint)f2bs(acc[1]) << 16);
    o.y = (uint)f2bs(acc[2]) | ((uint)f2bs(acc[3]) << 16);
    o.z = (uint)f2bs(acc[4]) | ((uint)f2bs(acc[5]) << 16);
    o.w = (uint)f2bs(acc[6]) | ((uint)f2bs(acc[7]) << 16);
    *reinterpret_cast<uint4*>(&agg[(size_t)node * LD + oct * 8]) = o;
}

// ---------------- bf16 MFMA GEMM: C = A @ Wt^T (+bias)(+relu), bf16 out ----------------
template <int KI, int LDA, int KO, int LDC, bool BIASRELU>
__global__ __launch_bounds__(256) void gemm_mfma(const ushort* __restrict__ A,
                                                 const ushort* __restrict__ Bt,
                                                 const float* __restrict__ bias,
                                                 ushort* __restrict__ C, int n) {
    __shared__ ushort sA[64][40];
    __shared__ ushort sB[64][40];
    const int t = threadIdx.x;
    const int row0 = blockIdx.x * 64;
    const int col0 = blockIdx.y * 64;
    const int wid = t >> 6, lane = t & 63;
    const int wr = wid >> 1, wc = wid & 1;
    const int lrow = lane & 15;
    const int kgrp = lane >> 4;
    const int srr = t >> 2;      // staging row 0..63
    const int skq = t & 3;       // staging k-octet
    f32x4 acc[2][2];
#pragma unroll
    for (int i = 0; i < 2; ++i)
#pragma unroll
        for (int j = 0; j < 2; ++j) acc[i][j] = (f32x4)0.f;

    const int nk = (KI + 31) / 32;
    for (int ks = 0; ks < nk; ++ks) {
        const int kbase = ks * 32 + skq * 8;
        {   // stage A tile (64 rows x 32 k)
            int grow = row0 + srr;
            uint4 v = {0, 0, 0, 0};
            if (grow < n && kbase < LDA)
                v = *reinterpret_cast<const uint4*>(&A[(size_t)grow * LDA + kbase]);
            *reinterpret_cast<uint4*>(&sA[srr][skq * 8]) = v;
        }
        {   // stage B tile (64 cols x 32 k)
            int gcol = col0 + srr;
            uint4 v = {0, 0, 0, 0};
            if (gcol < KO && kbase < LDA)
                v = *reinterpret_cast<const uint4*>(&Bt[(size_t)gcol * LDA + kbase]);
            *reinterpret_cast<uint4*>(&sB[srr][skq * 8]) = v;
        }
        __syncthreads();
        s16x8 a0 = *reinterpret_cast<const s16x8*>(&sA[wr * 32 + lrow][kgrp * 8]);
        s16x8 a1 = *reinterpret_cast<const s16x8*>(&sA[wr * 32 + 16 + lrow][kgrp * 8]);
        s16x8 b0 = *reinterpret_cast<const s16x8*>(&sB[wc * 32 + lrow][kgrp * 8]);
        s16x8 b1 = *reinterpret_cast<const s16x8*>(&sB[wc * 32 + 16 + lrow][kgrp * 8]);
        acc[0][0] = __builtin_amdgcn_mfma_f32_16x16x32_bf16(a0, b0, acc[0][0], 0, 0, 0);
        acc[0][1] = __builtin_amdgcn_mfma_f32_16x16x32_bf16(a0, b1, acc[0][1], 0, 0, 0);
        acc[1][0] = __builtin_amdgcn_mfma_f32_16x16x32_bf16(a1, b0, acc[1][0], 0, 0, 0);
        acc[1][1] = __builtin_amdgcn_mfma_f32_16x16x32_bf16(a1, b1, acc[1][1], 0, 0, 0);
        __syncthreads();
    }
#pragma unroll
    for (int fr = 0; fr < 2; ++fr)
#pragma unroll
        for (int fc = 0; fc < 2; ++fc)
#pragma unroll
            for (int r = 0; r < 4; ++r) {
                int row = row0 + wr * 32 + fr * 16 + kgrp * 4 + r;
                int col = col0 + wc * 32 + fc * 16 + lrow;
                if (row < n && col < LDC) {
                    float v = acc[fr][fc][r];
                    ushort o = 0;
                    if (col < KO) {
                        if (BIASRELU) v = fmaxf(v + bias[col], 0.f);
                        o = f2bs(v);
                    }
                    C[(size_t)row * LDC + col] = o;
                }
            }
}

// ---------------- segment max pool: node-parallel blocks + deterministic atomicMax ----------------
// h3 >= 0 (ReLU), so uint-bit compare == float compare and 0.0f is the identity.
// Block = 64-node slice; 312 threads scan their column (coalesced); flush per segment boundary.
__global__ __launch_bounds__(320) void seg_max_blk(const ushort* __restrict__ h,
                                                   const int* __restrict__ batch,
                                                   uint* __restrict__ g0u, int n) {
    __shared__ int sbatch[64];
    int n0 = blockIdx.x * 64;
    int n1 = min(n0 + 64, n);
    int f = threadIdx.x;
    if (f < 64) sbatch[f] = (n0 + f < n) ? batch[n0 + f] : -1;
    __syncthreads();
    if (f >= 312) return;
    int cur = sbatch[0];
    float m = 0.f;
    for (int i = 0; i < n1 - n0; ++i) {
        int b = sbatch[i];
        if (b != cur) {
            atomicMax(&g0u[(size_t)cur * 312 + f], __float_as_uint(m));
            m = 0.f;
            cur = b;
        }
        m = fmaxf(m, b2f(h[(size_t)(n0 + i) * 312 + f]));
    }
    atomicMax(&g0u[(size_t)cur * 312 + f], __float_as_uint(m));
}

// ---------------- head GEMM: K-split, 32x64 tile, fp32 partials ----------------
template <int KI, int KO, int KS>
__global__ __launch_bounds__(256) void gemm_head(const float* __restrict__ A,
                                                 const float* __restrict__ W,
                                                 float* __restrict__ partial, int n) {
    __shared__ float sA[16][34];
    __shared__ float sW[16][68];
    const int t = threadIdx.x;
    const int row0 = blockIdx.x * 32;
    const int col0 = blockIdx.y * 64;
    const int z = blockIdx.z;
    const int kbeg = z * KS;
    const int kend = min(KI, kbeg + KS);
    const int r0 = (t >> 4) * 2;   // 0..30 (even)
    const int c0 = (t & 15) * 4;   // 0..60 (quad)
    float acc[2][4] = {};
    for (int k0 = kbeg; k0 < kend; k0 += 16) {
        {   // stage A: 32 rows x 16 k
            int row = t >> 3, kk = (t & 7) * 2;
            int grow = row0 + row;
#pragma unroll
            for (int j = 0; j < 2; ++j) {
                float v = 0.f;
                if (grow < n && (k0 + kk + j) < kend) v = A[(size_t)grow * KI + k0 + kk + j];
                sA[kk + j][row] = v;
            }
        }
        {   // stage W: 16 k x 64 cols
            int kk = t >> 4, cc = (t & 15) * 4;
#pragma unroll
            for (int j = 0; j < 4; ++j) {
                float v = 0.f;
                if ((k0 + kk) < kend) v = W[(size_t)(k0 + kk) * KO + col0 + cc + j];
                sW[kk][cc + j] = v;
            }
        }
        __syncthreads();
#pragma unroll 8
        for (int k = 0; k < 16; ++k) {
            float2 a = *reinterpret_cast<const float2*>(&sA[k][r0]);
            float4 w = *reinterpret_cast<const float4*>(&sW[k][c0]);
            acc[0][0] = fmaf(a.x, w.x, acc[0][0]); acc[0][1] = fmaf(a.x, w.y, acc[0][1]);
            acc[0][2] = fmaf(a.x, w.z, acc[0][2]); acc[0][3] = fmaf(a.x, w.w, acc[0][3]);
            acc[1][0] = fmaf(a.y, w.x, acc[1][0]); acc[1][1] = fmaf(a.y, w.y, acc[1][1]);
            acc[1][2] = fmaf(a.y, w.z, acc[1][2]); acc[1][3] = fmaf(a.y, w.w, acc[1][3]);
        }
        __syncthreads();
    }
#pragma unroll
    for (int ri = 0; ri < 2; ++ri) {
        int row = row0 + r0 + ri;
        if (row >= n) continue;
        *reinterpret_cast<float4*>(&partial[((size_t)z * n + row) * KO + col0 + c0]) =
            make_float4(acc[ri][0], acc[ri][1], acc[ri][2], acc[ri][3]);
    }
}

// sum partials over splits + bias (+relu), scatter into C[row*ldc + col_off + col]
template <int NS, bool RELU>
__global__ void head_reduce(const float* __restrict__ partial, const float* __restrict__ bias,
                            float* __restrict__ C, int n, int KO, int ldc, int col_off) {
    int j = blockIdx.x * blockDim.x + threadIdx.x;
    if (j >= n * KO) return;
    int row = j / KO, col = j % KO;
    float acc = bias[col];
#pragma unroll
    for (int s = 0; s < NS; ++s) acc += partial[((size_t)s * n + row) * KO + col];
    if (RELU) acc = fmaxf(acc, 0.f);
    C[(size_t)row * ldc + col_off + col] = acc;
}

// ---------------- Conv1d as implicit GEMM via MFMA (bf16), K-split ----------------
__global__ __launch_bounds__(256) void conv_mfma(const float* __restrict__ T,
                                                 const ushort* __restrict__ Kbf,
                                                 float* __restrict__ partial) {
    __shared__ ushort sA[64][40];
    __shared__ ushort sB[32][40];
    const int t = threadIdx.x;
    const int row0 = blockIdx.x * 64;
    const int split = blockIdx.y;
    const int kbeg = split * CONV_KCHUNK;
    const int kend = min(6000, kbeg + CONV_KCHUNK);
    const int wid = t >> 6, lane = t & 63;
    const int lrow = lane & 15, kgrp = lane >> 4;
    f32x4 acc0 = (f32x4)0.f, acc1 = (f32x4)0.f;
    for (int k0 = kbeg; k0 < kend; k0 += 32) {
        {   // stage A (64 rows x 32 k): load fp32 T, convert to bf16 (kb multiple of 8)
            int rr = t >> 2, kq = t & 3;
            int grow = row0 + rr;                 // < 6144 always
            int b = grow / 12, h = grow % 12;
            int kb = k0 + kq * 8;
            int i = kb >> 3;
            const float* tp = &T[(size_t)b * 14250 + (size_t)i * 19 + h];
            ushort u[8];
#pragma unroll
            for (int j = 0; j < 8; ++j)
                u[j] = (kb + j < kend) ? f2bs(tp[j]) : (ushort)0;
            uint4 v;
            v.x = (uint)u[0] | ((uint)u[1] << 16);
            v.y = (uint)u[2] | ((uint)u[3] << 16);
            v.z = (uint)u[4] | ((uint)u[5] << 16);
            v.w = (uint)u[6] | ((uint)u[7] << 16);
            *reinterpret_cast<uint4*>(&sA[rr][kq * 8]) = v;
        }
        if (t < 128) {   // stage B (32 outs x 32 k) from padded Kbf
            int o = t >> 2, kq = t & 3;
            uint4 v = *reinterpret_cast<const uint4*>(&Kbf[(size_t)o * 6016 + k0 + kq * 8]);
            *reinterpret_cast<uint4*>(&sB[o][kq * 8]) = v;
        }
        __syncthreads();
        s16x8 a0 = *reinterpret_cast<const s16x8*>(&sA[wid * 16 + lrow][kgrp * 8]);
        s16x8 b0 = *reinterpret_cast<const s16x8*>(&sB[lrow][kgrp * 8]);
        s16x8 b1 = *reinterpret_cast<const s16x8*>(&sB[16 + lrow][kgrp * 8]);
        acc0 = __builtin_amdgcn_mfma_f32_16x16x32_bf16(a0, b0, acc0, 0, 0, 0);
        acc1 = __builtin_amdgcn_mfma_f32_16x16x32_bf16(a0, b1, acc1, 0, 0, 0);
        __syncthreads();
    }
#pragma unroll
    for (int r = 0; r < 4; ++r) {
        int row = row0 + wid * 16 + kgrp * 4 + r;   // C/D: row=(lane>>4)*4+reg, col=lane&15
        int b = row / 12, h = row % 12;
        partial[(((size_t)split * NBATCH + b) * 32 + lrow) * 12 + h] = acc0[r];
        partial[(((size_t)split * NBATCH + b) * 32 + (16 + lrow)) * 12 + h] = acc1[r];
    }
}

__global__ void conv_reduce(const float* __restrict__ partial, const float* __restrict__ bxt,
                            float* __restrict__ convb) {
    int j = blockIdx.x * blockDim.x + threadIdx.x;
    if (j >= NBATCH * 384) return;
    int b = j / 384, rem = j % 384;
    int o = rem / 12, h = rem % 12;
    float acc = bxt[o];
#pragma unroll
    for (int s = 0; s < CONV_KSPLIT; ++s)
        acc += partial[(((size_t)s * NBATCH + b) * 32 + o) * 12 + h];
    convb[j] = acc;
}

// ---------------- final [512,512] @ [512,1] ----------------
__global__ void final_out(const float* __restrict__ f2, const float* __restrict__ Wo,
                          const float* __restrict__ bo, float* __restrict__ out) {
    int row = blockIdx.x * (blockDim.x / 64) + (threadIdx.x / 64);
    int lane = threadIdx.x & 63;
    if (row >= NBATCH) return;
    float acc = 0.f;
    for (int k = lane; k < 512; k += 64) acc = fmaf(f2[(size_t)row * 512 + k], Wo[k], acc);
#pragma unroll
    for (int off = 32; off > 0; off >>= 1) acc += __shfl_down(acc, off);
    if (lane == 0) out[row] = acc + bo[0];
}

extern "C" void kernel_launch(void* const* d_in, const int* in_sizes, int n_in,
                              void* d_out, int out_size, void* d_ws, size_t ws_size,
                              hipStream_t stream) {
    (void)in_sizes; (void)n_in; (void)out_size; (void)ws_size;
    const float* x     = (const float*)d_in[0];
    const int*   ei    = (const int*)d_in[1];
    const int*   batch = (const int*)d_in[2];
    const float* T     = (const float*)d_in[3];
    const float* W1 = (const float*)d_in[4];   const float* b1 = (const float*)d_in[5];
    const float* W2 = (const float*)d_in[6];   const float* b2 = (const float*)d_in[7];
    const float* W3 = (const float*)d_in[8];   const float* b3 = (const float*)d_in[9];
    const float* Wg1 = (const float*)d_in[10]; const float* bg1 = (const float*)d_in[11];
    const float* Wg2 = (const float*)d_in[12]; const float* bg2 = (const float*)d_in[13];
    const float* Kxt = (const float*)d_in[14]; const float* bxt = (const float*)d_in[15];
    const float* Wxt = (const float*)d_in[16]; const float* bxt2 = (const float*)d_in[17];
    const float* Wf1 = (const float*)d_in[18]; const float* bf1 = (const float*)d_in[19];
    const float* Wf2 = (const float*)d_in[20]; const float* bf2 = (const float*)d_in[21];
    const float* Wo = (const float*)d_in[22];  const float* bo = (const float*)d_in[23];
    const int* src = ei;
    const int* dst = ei + N_EDGESC;

    char* ws = (char*)d_ws;
    size_t off = 0;
    auto alloc = [&](size_t bytes) -> void* {
        void* p = ws + off;
        off += (bytes + 255) & ~(size_t)255;
        return p;
    };
    // ~139 MB total
    int*   deg      = (int*)alloc((size_t)N_NODESC * 4);
    float* dinv     = (float*)alloc((size_t)N_NODESC * 4);
    int*   row_ptr  = (int*)alloc((size_t)(N_NODESC + 1) * 4);
    int*   fillc    = (int*)alloc((size_t)N_NODESC * 4);
    int*   csr_src  = (int*)alloc((size_t)N_EDGESC * 4);
    int*   csums    = (int*)alloc((size_t)4096 * 4);
    float* g0       = (float*)alloc((size_t)NBATCH * 312 * 4);
    float* g1       = (float*)alloc((size_t)NBATCH * 1024 * 4);
    float* convb    = (float*)alloc((size_t)NBATCH * 384 * 4);
    float* xc       = (float*)alloc((size_t)NBATCH * 256 * 4);
    float* f1       = (float*)alloc((size_t)NBATCH * 1024 * 4);
    float* f2       = (float*)alloc((size_t)NBATCH * 512 * 4);
    float* cpart    = (float*)alloc((size_t)CONV_KSPLIT * NBATCH * 32 * 12 * 4);
    float* hpart    = (float*)alloc((size_t)8 * NBATCH * 128 * 4);  // 2MB: all head splits fit
    ushort* xbf     = (ushort*)alloc((size_t)N_NODESC * 80 * 2);   // x (80) -> later h1 (80)
    ushort* aggbuf  = (ushort*)alloc((size_t)N_NODESC * 160 * 2);  // agg1/2 (80), agg3 (160)
    ushort* hbuf    = (ushort*)alloc((size_t)N_NODESC * 312 * 2);  // h2 (160), h3 (312)
    ushort* Wt1     = (ushort*)alloc((size_t)78 * 80 * 2);
    ushort* Wt2     = (ushort*)alloc((size_t)156 * 80 * 2);
    ushort* Wt3     = (ushort*)alloc((size_t)312 * 160 * 2);
    ushort* Kbf     = (ushort*)alloc((size_t)32 * 6016 * 2);
    float* out      = (float*)d_out;

    const int TPB = 256;

    // ---- graph structure ----
    zero_ints<<<divup(N_NODESC, TPB), TPB, 0, stream>>>(deg, N_NODESC);
    count_deg<<<divup(N_EDGESC, TPB), TPB, 0, stream>>>(dst, deg, N_EDGESC);
    compute_dinv<<<divup(N_NODESC, TPB), TPB, 0, stream>>>(deg, dinv, N_NODESC);
    int nchunks = divup(N_NODESC, SCAN_CHUNK);
    scan_chunks<<<nchunks, 256, 0, stream>>>(deg, row_ptr, csums, N_NODESC);
    scan_sums<<<1, 64, 0, stream>>>(csums, nchunks);
    finalize_rowptr<<<divup(N_NODESC, TPB), TPB, 0, stream>>>(row_ptr, csums, fillc, N_NODESC, N_EDGESC);
    fill_csr<<<divup(N_EDGESC, TPB), TPB, 0, stream>>>(src, dst, fillc, csr_src, N_EDGESC);

    // ---- bf16 conversions ----
    convert_x_bf16<<<divup(N_NODESC * 80, TPB), TPB, 0, stream>>>(x, xbf, N_NODESC, 78, 80);
    transpose_w_bf16<<<divup(78 * 80, TPB), TPB, 0, stream>>>(W1, Wt1, 78, 78, 80);
    transpose_w_bf16<<<divup(156 * 80, TPB), TPB, 0, stream>>>(W2, Wt2, 78, 156, 80);
    transpose_w_bf16<<<divup(312 * 160, TPB), TPB, 0, stream>>>(W3, Wt3, 156, 312, 160);
    convert_k_bf16<<<divup(32 * 6016, TPB), TPB, 0, stream>>>(Kxt, Kbf);

    // ---- GCN layer 1: agg(x) -> gemm+bias+relu -> h1 (LD 80) ----
    gcn_gather_vec<80><<<divup(N_NODESC * 10, TPB), TPB, 0, stream>>>(
        xbf, row_ptr, csr_src, dinv, aggbuf, N_NODESC);
    gemm_mfma<78, 80, 78, 80, true><<<dim3(divup(N_NODESC, 64), 2), 256, 0, stream>>>(
        aggbuf, Wt1, b1, xbf, N_NODESC);   // h1 overwrites xbf (x dead)

    // ---- GCN layer 2: agg(h1) -> gemm -> h2 (LD 160) ----
    gcn_gather_vec<80><<<divup(N_NODESC * 10, TPB), TPB, 0, stream>>>(
        xbf, row_ptr, csr_src, dinv, aggbuf, N_NODESC);
    gemm_mfma<78, 80, 156, 160, true><<<dim3(divup(N_NODESC, 64), 3), 256, 0, stream>>>(
        aggbuf, Wt2, b2, hbuf, N_NODESC);

    // ---- GCN layer 3: agg(h2) -> gemm -> h3 (LD 312) ----
    gcn_gather_vec<160><<<divup(N_NODESC * 20, TPB), TPB, 0, stream>>>(
        hbuf, row_ptr, csr_src, dinv, aggbuf, N_NODESC);
    gemm_mfma<156, 160, 312, 312, true><<<dim3(divup(N_NODESC, 64), 5), 256, 0, stream>>>(
        aggbuf, Wt3, b3, hbuf, N_NODESC);

    // ---- global max pool (node-parallel + deterministic atomicMax on nonneg floats) ----
    zero_ints<<<divup(NBATCH * 312, TPB), TPB, 0, stream>>>((int*)g0, NBATCH * 312);
    seg_max_blk<<<divup(N_NODESC, 64), 320, 0, stream>>>(hbuf, batch, (uint*)g0, N_NODESC);

    // ---- graph head: g1 = relu(g0 @ Wg1 + bg1) ----
    gemm_head<312, 1024, 312><<<dim3(16, 16, 1), 256, 0, stream>>>(g0, Wg1, hpart, NBATCH);
    head_reduce<1, true><<<divup(NBATCH * 1024, TPB), TPB, 0, stream>>>(
        hpart, bg1, g1, NBATCH, 1024, 1024, 0);
    // xc[:, :128] = g1 @ Wg2 + bg2
    gemm_head<1024, 128, 128><<<dim3(16, 2, 8), 256, 0, stream>>>(g1, Wg2, hpart, NBATCH);
    head_reduce<8, false><<<divup(NBATCH * 128, TPB), TPB, 0, stream>>>(
        hpart, bg2, xc, NBATCH, 128, 256, 0);

    // ---- protein branch: implicit-GEMM conv via MFMA ----
    conv_mfma<<<dim3(6144 / 64, CONV_KSPLIT), 256, 0, stream>>>(T, Kbf, cpart);
    conv_reduce<<<divup(NBATCH * 384, TPB), TPB, 0, stream>>>(cpart, bxt, convb);
    // xc[:, 128:] = convb @ Wxt + bxt2
    gemm_head<384, 128, 48><<<dim3(16, 2, 8), 256, 0, stream>>>(convb, Wxt, hpart, NBATCH);
    head_reduce<8, false><<<divup(NBATCH * 128, TPB), TPB, 0, stream>>>(
        hpart, bxt2, xc, NBATCH, 128, 256, 128);

    // ---- fusion MLP ----
    gemm_head<256, 1024, 256><<<dim3(16, 16, 1), 256, 0, stream>>>(xc, Wf1, hpart, NBATCH);
    head_reduce<1, true><<<divup(NBATCH * 1024, TPB), TPB, 0, stream>>>(
        hpart, bf1, f1, NBATCH, 1024, 1024, 0);
    gemm_head<1024, 512, 512><<<dim3(16, 8, 2), 256, 0, stream>>>(f1, Wf2, hpart, NBATCH);
    head_reduce<2, true><<<divup(NBATCH * 512, TPB), TPB, 0, stream>>>(
        hpart, bf2, f2, NBATCH, 512, 512, 0);
    final_out<<<divup(NBATCH, 4), 256, 0, stream>>>(f2, Wo, bo, out);
}

// Round 13
// 496.431 us; speedup vs baseline: 1.1015x; 1.0188x over previous
//
#include <hip/hip_runtime.h>
#include <hip/hip_bf16.h>
#include <cstddef>
#include <cstdint>

#define N_NODESC 100000
#define N_EDGESC 500000
#define NBATCH   512
#define SCAN_CHUNK 1024
#define CONV_KSPLIT 16
#define CONV_KCHUNK 384    // multiple of 32 -> k-octets stay channel-aligned; last split ragged (240)

static inline int divup(int a, int b) { return (a + b - 1) / b; }

typedef __hip_bfloat16 bf16;
typedef short s16x8 __attribute__((ext_vector_type(8)));
typedef float f32x4 __attribute__((ext_vector_type(4)));

__device__ inline float b2f(ushort u) {
    union { uint i; float f; } c; c.i = (uint)u << 16; return c.f;
}
__device__ inline ushort f2bs(float v) {
    bf16 b = __float2bfloat16(v);
    return *reinterpret_cast<ushort*>(&b);
}
__device__ inline void unpack2(uint u, float& a, float& b) {
    union { uint i; float f; } lo, hi;
    lo.i = u << 16; hi.i = u & 0xffff0000u;
    a = lo.f; b = hi.f;
}

// ---------------- zero ints ----------------
__global__ void zero_ints(int* __restrict__ p, int n) {
    int i = blockIdx.x * blockDim.x + threadIdx.x;
    if (i < n) p[i] = 0;
}

// ---------------- degree / dinv ----------------
__global__ void count_deg(const int* __restrict__ dst, int* __restrict__ deg, int e) {
    int i = blockIdx.x * blockDim.x + threadIdx.x;
    if (i < e) atomicAdd(&deg[dst[i]], 1);
}

__global__ void compute_dinv(const int* __restrict__ deg, float* __restrict__ dinv, int n) {
    int i = blockIdx.x * blockDim.x + threadIdx.x;
    if (i < n) dinv[i] = 1.0f / sqrtf((float)deg[i] + 1.0f);
}

// ---------------- exclusive scan (3-phase) ----------------
__global__ void scan_chunks(const int* __restrict__ deg, int* __restrict__ out,
                            int* __restrict__ sums, int n) {
    __shared__ int sdata[256];
    int t = threadIdx.x;
    int base = blockIdx.x * SCAN_CHUNK;
    int v[4];
    int s = 0;
#pragma unroll
    for (int j = 0; j < 4; ++j) {
        int idx = base + t * 4 + j;
        v[j] = s;
        int d = (idx < n) ? deg[idx] : 0;
        s += d;
    }
    int x = s;
    sdata[t] = x;
    __syncthreads();
    for (int off = 1; off < 256; off <<= 1) {
        int y = (t >= off) ? sdata[t - off] : 0;
        __syncthreads();
        x += y;
        sdata[t] = x;
        __syncthreads();
    }
    int thread_excl = x - s;
    if (t == 255) sums[blockIdx.x] = x;
#pragma unroll
    for (int j = 0; j < 4; ++j) {
        int idx = base + t * 4 + j;
        if (idx < n) out[idx] = thread_excl + v[j];
    }
}

__global__ void scan_sums(int* sums, int nchunks) {
    if (threadIdx.x == 0 && blockIdx.x == 0) {
        int acc = 0;
        for (int i = 0; i < nchunks; ++i) { int v = sums[i]; sums[i] = acc; acc += v; }
    }
}

__global__ void finalize_rowptr(int* __restrict__ row_ptr, const int* __restrict__ sums,
                                int* __restrict__ fill, int n, int e) {
    int i = blockIdx.x * blockDim.x + threadIdx.x;
    if (i < n) {
        int v = row_ptr[i] + sums[i / SCAN_CHUNK];
        row_ptr[i] = v;
        fill[i] = v;
    }
    if (i == 0) row_ptr[n] = e;
}

__global__ void fill_csr(const int* __restrict__ src, const int* __restrict__ dst,
                         int* __restrict__ fill, int* __restrict__ csr_src, int e) {
    int i = blockIdx.x * blockDim.x + threadIdx.x;
    if (i < e) {
        int d = dst[i];
        int pos = atomicAdd(&fill[d], 1);
        csr_src[pos] = src[i];
    }
}

// ---------------- fp32 -> bf16 node features, scaled by dinv[node], padded stride ----------------
__global__ void convert_x_bf16(const float* __restrict__ x, const float* __restrict__ dinv,
                               ushort* __restrict__ xbf, int n, int ki, int ld) {
    int i = blockIdx.x * blockDim.x + threadIdx.x;
    int total = n * ld;
    if (i >= total) return;
    int node = i / ld, col = i % ld;
    xbf[i] = (col < ki) ? f2bs(x[(size_t)node * ki + col] * dinv[node]) : (ushort)0;
}

// ---------------- W[KI,KO] fp32 -> Wt[KO,LD] bf16 (transposed, zero-padded) ----------------
__global__ void transpose_w_bf16(const float* __restrict__ W, ushort* __restrict__ Wt,
                                 int ki, int ko, int ld) {
    int i = blockIdx.x * blockDim.x + threadIdx.x;
    int total = ko * ld;
    if (i >= total) return;
    int o = i / ld, k = i % ld;
    Wt[i] = (k < ki) ? f2bs(W[(size_t)k * ko + o]) : (ushort)0;
}

// ---------------- Kxt[32][6000] fp32 -> Kbf[32][6016] bf16 (zero-padded) ----------------
__global__ void convert_k_bf16(const float* __restrict__ Kxt, ushort* __restrict__ Kbf) {
    int i = blockIdx.x * blockDim.x + threadIdx.x;
    if (i >= 32 * 6016) return;
    int o = i / 6016, k = i % 6016;
    Kbf[i] = (k < 6000) ? f2bs(Kxt[(size_t)o * 6000 + k]) : (ushort)0;
}

// ---------------- vectorized GCN aggregation on dinv-prescaled features ----------------
// Input h' = h * dinv (per row). agg[d] = dinv[d] * (h'[d] + sum_{s in N(d)} h'[s]).
// No per-edge dinv load; per-edge op is pure add.
template <int LD>
__global__ void gcn_gather_vec(const ushort* __restrict__ h, const int* __restrict__ row_ptr,
                               const int* __restrict__ csr_src, const float* __restrict__ dinv,
                               ushort* __restrict__ agg, int n) {
    constexpr int TPN = LD / 8;
    int gid = blockIdx.x * blockDim.x + threadIdx.x;
    int node = gid / TPN, oct = gid % TPN;
    if (node >= n) return;
    float dn = dinv[node];
    int e0 = row_ptr[node], e1 = row_ptr[node + 1];
    float acc[8];
    {   // self term: h'[node]
        uint4 v = *reinterpret_cast<const uint4*>(&h[(size_t)node * LD + oct * 8]);
        unpack2(v.x, acc[0], acc[1]);
        unpack2(v.y, acc[2], acc[3]);
        unpack2(v.z, acc[4], acc[5]);
        unpack2(v.w, acc[6], acc[7]);
    }
    for (int e = e0; e < e1; ++e) {
        int s = csr_src[e];
        uint4 v = *reinterpret_cast<const uint4*>(&h[(size_t)s * LD + oct * 8]);
        float a, b;
        unpack2(v.x, a, b); acc[0] += a; acc[1] += b;
        unpack2(v.y, a, b); acc[2] += a; acc[3] += b;
        unpack2(v.z, a, b); acc[4] += a; acc[5] += b;
        unpack2(v.w, a, b); acc[6] += a; acc[7] += b;
    }
    uint4 o;
    o.x = (uint)f2bs(acc[0] * dn) | ((uint)f2bs(acc[1] * dn) << 16);
    o.y = (uint)f2bs(acc[2] * dn) | ((uint)f2bs(acc[3] * dn) << 16);
    o.z = (uint)f2bs(acc[4] * dn) | ((uint)f2bs(acc[5] * dn) << 16);
    o.w = (uint)f2bs(acc[6] * dn) | ((uint)f2bs(acc[7] * dn) << 16);
    *reinterpret_cast<uint4*>(&agg[(size_t)node * LD + oct * 8]) = o;
}

// ---------------- bf16 MFMA GEMM: C = A @ Wt^T (+bias+relu)(*rowscale), bf16 out ----------------
// 1D grid; NBY column-blocks per row-tile are ADJACENT (A-tile L2/L3 locality).
template <int KI, int LDA, int KO, int LDC, int NBY, bool SCALEROW>
__global__ __launch_bounds__(256) void gemm_mfma(const ushort* __restrict__ A,
                                                 const ushort* __restrict__ Bt,
                                                 const float* __restrict__ bias,
                                                 const float* __restrict__ rowscale,
                                                 ushort* __restrict__ C, int n) {
    __shared__ ushort sA[64][40];
    __shared__ ushort sB[64][40];
    const int t = threadIdx.x;
    const int row0 = (blockIdx.x / NBY) * 64;
    const int col0 = (blockIdx.x % NBY) * 64;
    const int wid = t >> 6, lane = t & 63;
    const int wr = wid >> 1, wc = wid & 1;
    const int lrow = lane & 15;
    const int kgrp = lane >> 4;
    const int srr = t >> 2;      // staging row 0..63
    const int skq = t & 3;       // staging k-octet
    f32x4 acc[2][2];
#pragma unroll
    for (int i = 0; i < 2; ++i)
#pragma unroll
        for (int j = 0; j < 2; ++j) acc[i][j] = (f32x4)0.f;

    const int nk = (KI + 31) / 32;
    for (int ks = 0; ks < nk; ++ks) {
        const int kbase = ks * 32 + skq * 8;
        {   // stage A tile (64 rows x 32 k)
            int grow = row0 + srr;
            uint4 v = {0, 0, 0, 0};
            if (grow < n && kbase < LDA)
                v = *reinterpret_cast<const uint4*>(&A[(size_t)grow * LDA + kbase]);
            *reinterpret_cast<uint4*>(&sA[srr][skq * 8]) = v;
        }
        {   // stage B tile (64 cols x 32 k)
            int gcol = col0 + srr;
            uint4 v = {0, 0, 0, 0};
            if (gcol < KO && kbase < LDA)
                v = *reinterpret_cast<const uint4*>(&Bt[(size_t)gcol * LDA + kbase]);
            *reinterpret_cast<uint4*>(&sB[srr][skq * 8]) = v;
        }
        __syncthreads();
        s16x8 a0 = *reinterpret_cast<const s16x8*>(&sA[wr * 32 + lrow][kgrp * 8]);
        s16x8 a1 = *reinterpret_cast<const s16x8*>(&sA[wr * 32 + 16 + lrow][kgrp * 8]);
        s16x8 b0 = *reinterpret_cast<const s16x8*>(&sB[wc * 32 + lrow][kgrp * 8]);
        s16x8 b1 = *reinterpret_cast<const s16x8*>(&sB[wc * 32 + 16 + lrow][kgrp * 8]);
        acc[0][0] = __builtin_amdgcn_mfma_f32_16x16x32_bf16(a0, b0, acc[0][0], 0, 0, 0);
        acc[0][1] = __builtin_amdgcn_mfma_f32_16x16x32_bf16(a0, b1, acc[0][1], 0, 0, 0);
        acc[1][0] = __builtin_amdgcn_mfma_f32_16x16x32_bf16(a1, b0, acc[1][0], 0, 0, 0);
        acc[1][1] = __builtin_amdgcn_mfma_f32_16x16x32_bf16(a1, b1, acc[1][1], 0, 0, 0);
        __syncthreads();
    }
#pragma unroll
    for (int fr = 0; fr < 2; ++fr)
#pragma unroll
        for (int fc = 0; fc < 2; ++fc)
#pragma unroll
            for (int r = 0; r < 4; ++r) {
                int row = row0 + wr * 32 + fr * 16 + kgrp * 4 + r;
                int col = col0 + wc * 32 + fc * 16 + lrow;
                if (row < n && col < LDC) {
                    float v = acc[fr][fc][r];
                    ushort o = 0;
                    if (col < KO) {
                        v = fmaxf(v + bias[col], 0.f);
                        if (SCALEROW) v *= rowscale[row];
                        o = f2bs(v);
                    }
                    C[(size_t)row * LDC + col] = o;
                }
            }
}

// ---------------- segment max pool: node-parallel blocks + deterministic atomicMax ----------------
__global__ __launch_bounds__(320) void seg_max_blk(const ushort* __restrict__ h,
                                                   const int* __restrict__ batch,
                                                   uint* __restrict__ g0u, int n) {
    __shared__ int sbatch[64];
    int n0 = blockIdx.x * 64;
    int n1 = min(n0 + 64, n);
    int f = threadIdx.x;
    if (f < 64) sbatch[f] = (n0 + f < n) ? batch[n0 + f] : -1;
    __syncthreads();
    if (f >= 312) return;
    int cur = sbatch[0];
    float m = 0.f;
    for (int i = 0; i < n1 - n0; ++i) {
        int b = sbatch[i];
        if (b != cur) {
            atomicMax(&g0u[(size_t)cur * 312 + f], __float_as_uint(m));
            m = 0.f;
            cur = b;
        }
        m = fmaxf(m, b2f(h[(size_t)(n0 + i) * 312 + f]));
    }
    atomicMax(&g0u[(size_t)cur * 312 + f], __float_as_uint(m));
}

// ---------------- head GEMM: K-split, 32x64 tile, fp32 partials ----------------
template <int KI, int KO, int KS>
__global__ __launch_bounds__(256) void gemm_head(const float* __restrict__ A,
                                                 const float* __restrict__ W,
                                                 float* __restrict__ partial, int n) {
    __shared__ float sA[16][34];
    __shared__ float sW[16][68];
    const int t = threadIdx.x;
    const int row0 = blockIdx.x * 32;
    const int col0 = blockIdx.y * 64;
    const int z = blockIdx.z;
    const int kbeg = z * KS;
    const int kend = min(KI, kbeg + KS);
    const int r0 = (t >> 4) * 2;   // 0..30 (even)
    const int c0 = (t & 15) * 4;   // 0..60 (quad)
    float acc[2][4] = {};
    for (int k0 = kbeg; k0 < kend; k0 += 16) {
        {   // stage A: 32 rows x 16 k
            int row = t >> 3, kk = (t & 7) * 2;
            int grow = row0 + row;
#pragma unroll
            for (int j = 0; j < 2; ++j) {
                float v = 0.f;
                if (grow < n && (k0 + kk + j) < kend) v = A[(size_t)grow * KI + k0 + kk + j];
                sA[kk + j][row] = v;
            }
        }
        {   // stage W: 16 k x 64 cols
            int kk = t >> 4, cc = (t & 15) * 4;
#pragma unroll
            for (int j = 0; j < 4; ++j) {
                float v = 0.f;
                if ((k0 + kk) < kend) v = W[(size_t)(k0 + kk) * KO + col0 + cc + j];
                sW[kk][cc + j] = v;
            }
        }
        __syncthreads();
#pragma unroll 8
        for (int k = 0; k < 16; ++k) {
            float2 a = *reinterpret_cast<const float2*>(&sA[k][r0]);
            float4 w = *reinterpret_cast<const float4*>(&sW[k][c0]);
            acc[0][0] = fmaf(a.x, w.x, acc[0][0]); acc[0][1] = fmaf(a.x, w.y, acc[0][1]);
            acc[0][2] = fmaf(a.x, w.z, acc[0][2]); acc[0][3] = fmaf(a.x, w.w, acc[0][3]);
            acc[1][0] = fmaf(a.y, w.x, acc[1][0]); acc[1][1] = fmaf(a.y, w.y, acc[1][1]);
            acc[1][2] = fmaf(a.y, w.z, acc[1][2]); acc[1][3] = fmaf(a.y, w.w, acc[1][3]);
        }
        __syncthreads();
    }
#pragma unroll
    for (int ri = 0; ri < 2; ++ri) {
        int row = row0 + r0 + ri;
        if (row >= n) continue;
        *reinterpret_cast<float4*>(&partial[((size_t)z * n + row) * KO + col0 + c0]) =
            make_float4(acc[ri][0], acc[ri][1], acc[ri][2], acc[ri][3]);
    }
}

// sum partials over splits + bias (+relu), scatter into C[row*ldc + col_off + col]
template <int NS, bool RELU>
__global__ void head_reduce(const float* __restrict__ partial, const float* __restrict__ bias,
                            float* __restrict__ C, int n, int KO, int ldc, int col_off) {
    int j = blockIdx.x * blockDim.x + threadIdx.x;
    if (j >= n * KO) return;
    int row = j / KO, col = j % KO;
    float acc = bias[col];
#pragma unroll
    for (int s = 0; s < NS; ++s) acc += partial[((size_t)s * n + row) * KO + col];
    if (RELU) acc = fmaxf(acc, 0.f);
    C[(size_t)row * ldc + col_off + col] = acc;
}

// ---------------- Conv1d as implicit GEMM via MFMA (bf16), K-split ----------------
__global__ __launch_bounds__(256) void conv_mfma(const float* __restrict__ T,
                                                 const ushort* __restrict__ Kbf,
                                                 float* __restrict__ partial) {
    __shared__ ushort sA[64][40];
    __shared__ ushort sB[32][40];
    const int t = threadIdx.x;
    const int row0 = blockIdx.x * 64;
    const int split = blockIdx.y;
    const int kbeg = split * CONV_KCHUNK;
    const int kend = min(6000, kbeg + CONV_KCHUNK);
    const int wid = t >> 6, lane = t & 63;
    const int lrow = lane & 15, kgrp = lane >> 4;
    f32x4 acc0 = (f32x4)0.f, acc1 = (f32x4)0.f;
    for (int k0 = kbeg; k0 < kend; k0 += 32) {
        {   // stage A (64 rows x 32 k): load fp32 T, convert to bf16 (kb multiple of 8)
            int rr = t >> 2, kq = t & 3;
            int grow = row0 + rr;                 // < 6144 always
            int b = grow / 12, h = grow % 12;
            int kb = k0 + kq * 8;
            int i = kb >> 3;
            const float* tp = &T[(size_t)b * 14250 + (size_t)i * 19 + h];
            ushort u[8];
#pragma unroll
            for (int j = 0; j < 8; ++j)
                u[j] = (kb + j < kend) ? f2bs(tp[j]) : (ushort)0;
            uint4 v;
            v.x = (uint)u[0] | ((uint)u[1] << 16);
            v.y = (uint)u[2] | ((uint)u[3] << 16);
            v.z = (uint)u[4] | ((uint)u[5] << 16);
            v.w = (uint)u[6] | ((uint)u[7] << 16);
            *reinterpret_cast<uint4*>(&sA[rr][kq * 8]) = v;
        }
        if (t < 128) {   // stage B (32 outs x 32 k) from padded Kbf
            int o = t >> 2, kq = t & 3;
            uint4 v = *reinterpret_cast<const uint4*>(&Kbf[(size_t)o * 6016 + k0 + kq * 8]);
            *reinterpret_cast<uint4*>(&sB[o][kq * 8]) = v;
        }
        __syncthreads();
        s16x8 a0 = *reinterpret_cast<const s16x8*>(&sA[wid * 16 + lrow][kgrp * 8]);
        s16x8 b0 = *reinterpret_cast<const s16x8*>(&sB[lrow][kgrp * 8]);
        s16x8 b1 = *reinterpret_cast<const s16x8*>(&sB[16 + lrow][kgrp * 8]);
        acc0 = __builtin_amdgcn_mfma_f32_16x16x32_bf16(a0, b0, acc0, 0, 0, 0);
        acc1 = __builtin_amdgcn_mfma_f32_16x16x32_bf16(a0, b1, acc1, 0, 0, 0);
        __syncthreads();
    }
#pragma unroll
    for (int r = 0; r < 4; ++r) {
        int row = row0 + wid * 16 + kgrp * 4 + r;   // C/D: row=(lane>>4)*4+reg, col=lane&15
        int b = row / 12, h = row % 12;
        partial[(((size_t)split * NBATCH + b) * 32 + lrow) * 12 + h] = acc0[r];
        partial[(((size_t)split * NBATCH + b) * 32 + (16 + lrow)) * 12 + h] = acc1[r];
    }
}

__global__ void conv_reduce(const float* __restrict__ partial, const float* __restrict__ bxt,
                            float* __restrict__ convb) {
    int j = blockIdx.x * blockDim.x + threadIdx.x;
    if (j >= NBATCH * 384) return;
    int b = j / 384, rem = j % 384;
    int o = rem / 12, h = rem % 12;
    float acc = bxt[o];
#pragma unroll
    for (int s = 0; s < CONV_KSPLIT; ++s)
        acc += partial[(((size_t)s * NBATCH + b) * 32 + o) * 12 + h];
    convb[j] = acc;
}

// ---------------- final [512,512] @ [512,1] ----------------
__global__ void final_out(const float* __restrict__ f2, const float* __restrict__ Wo,
                          const float* __restrict__ bo, float* __restrict__ out) {
    int row = blockIdx.x * (blockDim.x / 64) + (threadIdx.x / 64);
    int lane = threadIdx.x & 63;
    if (row >= NBATCH) return;
    float acc = 0.f;
    for (int k = lane; k < 512; k += 64) acc = fmaf(f2[(size_t)row * 512 + k], Wo[k], acc);
#pragma unroll
    for (int off = 32; off > 0; off >>= 1) acc += __shfl_down(acc, off);
    if (lane == 0) out[row] = acc + bo[0];
}

extern "C" void kernel_launch(void* const* d_in, const int* in_sizes, int n_in,
                              void* d_out, int out_size, void* d_ws, size_t ws_size,
                              hipStream_t stream) {
    (void)in_sizes; (void)n_in; (void)out_size; (void)ws_size;
    const float* x     = (const float*)d_in[0];
    const int*   ei    = (const int*)d_in[1];
    const int*   batch = (const int*)d_in[2];
    const float* T     = (const float*)d_in[3];
    const float* W1 = (const float*)d_in[4];   const float* b1 = (const float*)d_in[5];
    const float* W2 = (const float*)d_in[6];   const float* b2 = (const float*)d_in[7];
    const float* W3 = (const float*)d_in[8];   const float* b3 = (const float*)d_in[9];
    const float* Wg1 = (const float*)d_in[10]; const float* bg1 = (const float*)d_in[11];
    const float* Wg2 = (const float*)d_in[12]; const float* bg2 = (const float*)d_in[13];
    const float* Kxt = (const float*)d_in[14]; const float* bxt = (const float*)d_in[15];
    const float* Wxt = (const float*)d_in[16]; const float* bxt2 = (const float*)d_in[17];
    const float* Wf1 = (const float*)d_in[18]; const float* bf1 = (const float*)d_in[19];
    const float* Wf2 = (const float*)d_in[20]; const float* bf2 = (const float*)d_in[21];
    const float* Wo = (const float*)d_in[22];  const float* bo = (const float*)d_in[23];
    const int* src = ei;
    const int* dst = ei + N_EDGESC;

    char* ws = (char*)d_ws;
    size_t off = 0;
    auto alloc = [&](size_t bytes) -> void* {
        void* p = ws + off;
        off += (bytes + 255) & ~(size_t)255;
        return p;
    };
    // ~139 MB total
    int*   deg      = (int*)alloc((size_t)N_NODESC * 4);
    float* dinv     = (float*)alloc((size_t)N_NODESC * 4);
    int*   row_ptr  = (int*)alloc((size_t)(N_NODESC + 1) * 4);
    int*   fillc    = (int*)alloc((size_t)N_NODESC * 4);
    int*   csr_src  = (int*)alloc((size_t)N_EDGESC * 4);
    int*   csums    = (int*)alloc((size_t)4096 * 4);
    float* g0       = (float*)alloc((size_t)NBATCH * 312 * 4);
    float* g1       = (float*)alloc((size_t)NBATCH * 1024 * 4);
    float* convb    = (float*)alloc((size_t)NBATCH * 384 * 4);
    float* xc       = (float*)alloc((size_t)NBATCH * 256 * 4);
    float* f1       = (float*)alloc((size_t)NBATCH * 1024 * 4);
    float* f2       = (float*)alloc((size_t)NBATCH * 512 * 4);
    float* cpart    = (float*)alloc((size_t)CONV_KSPLIT * NBATCH * 32 * 12 * 4);
    float* hpart    = (float*)alloc((size_t)8 * NBATCH * 128 * 4);  // 2MB: all head splits fit
    ushort* xbf     = (ushort*)alloc((size_t)N_NODESC * 80 * 2);   // x' (80) -> later h1' (80)
    ushort* aggbuf  = (ushort*)alloc((size_t)N_NODESC * 160 * 2);  // agg1/2 (80), agg3 (160)
    ushort* hbuf    = (ushort*)alloc((size_t)N_NODESC * 312 * 2);  // h2' (160), h3 (312)
    ushort* Wt1     = (ushort*)alloc((size_t)78 * 80 * 2);
    ushort* Wt2     = (ushort*)alloc((size_t)156 * 80 * 2);
    ushort* Wt3     = (ushort*)alloc((size_t)312 * 160 * 2);
    ushort* Kbf     = (ushort*)alloc((size_t)32 * 6016 * 2);
    float* out      = (float*)d_out;

    const int TPB = 256;

    // ---- graph structure ----
    zero_ints<<<divup(N_NODESC, TPB), TPB, 0, stream>>>(deg, N_NODESC);
    count_deg<<<divup(N_EDGESC, TPB), TPB, 0, stream>>>(dst, deg, N_EDGESC);
    compute_dinv<<<divup(N_NODESC, TPB), TPB, 0, stream>>>(deg, dinv, N_NODESC);
    int nchunks = divup(N_NODESC, SCAN_CHUNK);
    scan_chunks<<<nchunks, 256, 0, stream>>>(deg, row_ptr, csums, N_NODESC);
    scan_sums<<<1, 64, 0, stream>>>(csums, nchunks);
    finalize_rowptr<<<divup(N_NODESC, TPB), TPB, 0, stream>>>(row_ptr, csums, fillc, N_NODESC, N_EDGESC);
    fill_csr<<<divup(N_EDGESC, TPB), TPB, 0, stream>>>(src, dst, fillc, csr_src, N_EDGESC);

    // ---- bf16 conversions (x folded with dinv) ----
    convert_x_bf16<<<divup(N_NODESC * 80, TPB), TPB, 0, stream>>>(x, dinv, xbf, N_NODESC, 78, 80);
    transpose_w_bf16<<<divup(78 * 80, TPB), TPB, 0, stream>>>(W1, Wt1, 78, 78, 80);
    transpose_w_bf16<<<divup(156 * 80, TPB), TPB, 0, stream>>>(W2, Wt2, 78, 156, 80);
    transpose_w_bf16<<<divup(312 * 160, TPB), TPB, 0, stream>>>(W3, Wt3, 156, 312, 160);
    convert_k_bf16<<<divup(32 * 6016, TPB), TPB, 0, stream>>>(Kxt, Kbf);

    // ---- GCN layer 1: agg(x') -> gemm(+bias+relu, *dinv) -> h1' (LD 80) ----
    gcn_gather_vec<80><<<divup(N_NODESC * 10, TPB), TPB, 0, stream>>>(
        xbf, row_ptr, csr_src, dinv, aggbuf, N_NODESC);
    gemm_mfma<78, 80, 78, 80, 2, true><<<divup(N_NODESC, 64) * 2, 256, 0, stream>>>(
        aggbuf, Wt1, b1, dinv, xbf, N_NODESC);   // h1' overwrites xbf

    // ---- GCN layer 2: agg(h1') -> gemm(*dinv) -> h2' (LD 160) ----
    gcn_gather_vec<80><<<divup(N_NODESC * 10, TPB), TPB, 0, stream>>>(
        xbf, row_ptr, csr_src, dinv, aggbuf, N_NODESC);
    gemm_mfma<78, 80, 156, 160, 3, true><<<divup(N_NODESC, 64) * 3, 256, 0, stream>>>(
        aggbuf, Wt2, b2, dinv, hbuf, N_NODESC);

    // ---- GCN layer 3: agg(h2') -> gemm (no scale) -> h3 (LD 312) ----
    gcn_gather_vec<160><<<divup(N_NODESC * 20, TPB), TPB, 0, stream>>>(
        hbuf, row_ptr, csr_src, dinv, aggbuf, N_NODESC);
    gemm_mfma<156, 160, 312, 312, 5, false><<<divup(N_NODESC, 64) * 5, 256, 0, stream>>>(
        aggbuf, Wt3, b3, nullptr, hbuf, N_NODESC);

    // ---- global max pool (node-parallel + deterministic atomicMax on nonneg floats) ----
    zero_ints<<<divup(NBATCH * 312, TPB), TPB, 0, stream>>>((int*)g0, NBATCH * 312);
    seg_max_blk<<<divup(N_NODESC, 64), 320, 0, stream>>>(hbuf, batch, (uint*)g0, N_NODESC);

    // ---- graph head: g1 = relu(g0 @ Wg1 + bg1) ----
    gemm_head<312, 1024, 312><<<dim3(16, 16, 1), 256, 0, stream>>>(g0, Wg1, hpart, NBATCH);
    head_reduce<1, true><<<divup(NBATCH * 1024, TPB), TPB, 0, stream>>>(
        hpart, bg1, g1, NBATCH, 1024, 1024, 0);
    // xc[:, :128] = g1 @ Wg2 + bg2
    gemm_head<1024, 128, 128><<<dim3(16, 2, 8), 256, 0, stream>>>(g1, Wg2, hpart, NBATCH);
    head_reduce<8, false><<<divup(NBATCH * 128, TPB), TPB, 0, stream>>>(
        hpart, bg2, xc, NBATCH, 128, 256, 0);

    // ---- protein branch: implicit-GEMM conv via MFMA ----
    conv_mfma<<<dim3(6144 / 64, CONV_KSPLIT), 256, 0, stream>>>(T, Kbf, cpart);
    conv_reduce<<<divup(NBATCH * 384, TPB), TPB, 0, stream>>>(cpart, bxt, convb);
    // xc[:, 128:] = convb @ Wxt + bxt2
    gemm_head<384, 128, 48><<<dim3(16, 2, 8), 256, 0, stream>>>(convb, Wxt, hpart, NBATCH);
    head_reduce<8, false><<<divup(NBATCH * 128, TPB), TPB, 0, stream>>>(
        hpart, bxt2, xc, NBATCH, 128, 256, 128);

    // ---- fusion MLP ----
    gemm_head<256, 1024, 256><<<dim3(16, 16, 1), 256, 0, stream>>>(xc, Wf1, hpart, NBATCH);
    head_reduce<1, true><<<divup(NBATCH * 1024, TPB), TPB, 0, stream>>>(
        hpart, bf1, f1, NBATCH, 1024, 1024, 0);
    gemm_head<1024, 512, 512><<<dim3(16, 8, 2), 256, 0, stream>>>(f1, Wf2, hpart, NBATCH);
    head_reduce<2, true><<<divup(NBATCH * 512, TPB), TPB, 0, stream>>>(
        hpart, bf2, f2, NBATCH, 512, 512, 0);
    final_out<<<divup(NBATCH, 4), 256, 0, stream>>>(f2, Wo, bo, out);
}

// Round 14
// 443.996 us; speedup vs baseline: 1.2315x; 1.1181x over previous
//
#include <hip/hip_runtime.h>
#include <hip/hip_bf16.h>
#include <cstddef>
#include <cstdint>

#define N_NODESC 100000
#define N_EDGESC 500000
#define NBATCH   512
#define SCAN_CHUNK 1024
#define CONV_KSPLIT 16
#define CONV_KCHUNK 384    // multiple of 32 -> k-octets stay channel-aligned; last split ragged (240)

static inline int divup(int a, int b) { return (a + b - 1) / b; }

typedef __hip_bfloat16 bf16;
typedef short s16x8 __attribute__((ext_vector_type(8)));
typedef float f32x4 __attribute__((ext_vector_type(4)));

__device__ inline float b2f(ushort u) {
    union { uint i; float f; } c; c.i = (uint)u << 16; return c.f;
}
__device__ inline ushort f2bs(float v) {
    bf16 b = __float2bfloat16(v);
    return *reinterpret_cast<ushort*>(&b);
}
__device__ inline void unpack2(uint u, float& a, float& b) {
    union { uint i; float f; } lo, hi;
    lo.i = u << 16; hi.i = u & 0xffff0000u;
    a = lo.f; b = hi.f;
}

// ---------------- zero ints ----------------
__global__ void zero_ints(int* __restrict__ p, int n) {
    int i = blockIdx.x * blockDim.x + threadIdx.x;
    if (i < n) p[i] = 0;
}

// ---------------- degree / dinv ----------------
__global__ void count_deg(const int* __restrict__ dst, int* __restrict__ deg, int e) {
    int i = blockIdx.x * blockDim.x + threadIdx.x;
    if (i < e) atomicAdd(&deg[dst[i]], 1);
}

__global__ void compute_dinv(const int* __restrict__ deg, float* __restrict__ dinv, int n) {
    int i = blockIdx.x * blockDim.x + threadIdx.x;
    if (i < n) dinv[i] = 1.0f / sqrtf((float)deg[i] + 1.0f);
}

// ---------------- exclusive scan (3-phase) ----------------
__global__ void scan_chunks(const int* __restrict__ deg, int* __restrict__ out,
                            int* __restrict__ sums, int n) {
    __shared__ int sdata[256];
    int t = threadIdx.x;
    int base = blockIdx.x * SCAN_CHUNK;
    int v[4];
    int s = 0;
#pragma unroll
    for (int j = 0; j < 4; ++j) {
        int idx = base + t * 4 + j;
        v[j] = s;
        int d = (idx < n) ? deg[idx] : 0;
        s += d;
    }
    int x = s;
    sdata[t] = x;
    __syncthreads();
    for (int off = 1; off < 256; off <<= 1) {
        int y = (t >= off) ? sdata[t - off] : 0;
        __syncthreads();
        x += y;
        sdata[t] = x;
        __syncthreads();
    }
    int thread_excl = x - s;
    if (t == 255) sums[blockIdx.x] = x;
#pragma unroll
    for (int j = 0; j < 4; ++j) {
        int idx = base + t * 4 + j;
        if (idx < n) out[idx] = thread_excl + v[j];
    }
}

__global__ void scan_sums(int* sums, int nchunks) {
    if (threadIdx.x == 0 && blockIdx.x == 0) {
        int acc = 0;
        for (int i = 0; i < nchunks; ++i) { int v = sums[i]; sums[i] = acc; acc += v; }
    }
}

__global__ void finalize_rowptr(int* __restrict__ row_ptr, const int* __restrict__ sums,
                                int* __restrict__ fill, int n, int e) {
    int i = blockIdx.x * blockDim.x + threadIdx.x;
    if (i < n) {
        int v = row_ptr[i] + sums[i / SCAN_CHUNK];
        row_ptr[i] = v;
        fill[i] = v;
    }
    if (i == 0) row_ptr[n] = e;
}

__global__ void fill_csr(const int* __restrict__ src, const int* __restrict__ dst,
                         int* __restrict__ fill, int* __restrict__ csr_src, int e) {
    int i = blockIdx.x * blockDim.x + threadIdx.x;
    if (i < e) {
        int d = dst[i];
        int pos = atomicAdd(&fill[d], 1);
        csr_src[pos] = src[i];
    }
}

// ---------------- fp32 -> bf16 node features, scaled by dinv[node], padded stride ----------------
__global__ void convert_x_bf16(const float* __restrict__ x, const float* __restrict__ dinv,
                               ushort* __restrict__ xbf, int n, int ki, int ld) {
    int i = blockIdx.x * blockDim.x + threadIdx.x;
    int total = n * ld;
    if (i >= total) return;
    int node = i / ld, col = i % ld;
    xbf[i] = (col < ki) ? f2bs(x[(size_t)node * ki + col] * dinv[node]) : (ushort)0;
}

// ---------------- W[KI,KO] fp32 -> Wt[KO,LD] bf16 (transposed, zero-padded) ----------------
__global__ void transpose_w_bf16(const float* __restrict__ W, ushort* __restrict__ Wt,
                                 int ki, int ko, int ld) {
    int i = blockIdx.x * blockDim.x + threadIdx.x;
    int total = ko * ld;
    if (i >= total) return;
    int o = i / ld, k = i % ld;
    Wt[i] = (k < ki) ? f2bs(W[(size_t)k * ko + o]) : (ushort)0;
}

// ---------------- Kxt[32][6000] fp32 -> Kbf[32][6016] bf16 (zero-padded) ----------------
__global__ void convert_k_bf16(const float* __restrict__ Kxt, ushort* __restrict__ Kbf) {
    int i = blockIdx.x * blockDim.x + threadIdx.x;
    if (i >= 32 * 6016) return;
    int o = i / 6016, k = i % 6016;
    Kbf[i] = (k < 6000) ? f2bs(Kxt[(size_t)o * 6000 + k]) : (ushort)0;
}

// ---------------- vectorized GCN aggregation on dinv-prescaled features ----------------
template <int LD>
__global__ void gcn_gather_vec(const ushort* __restrict__ h, const int* __restrict__ row_ptr,
                               const int* __restrict__ csr_src, const float* __restrict__ dinv,
                               ushort* __restrict__ agg, int n) {
    constexpr int TPN = LD / 8;
    int gid = blockIdx.x * blockDim.x + threadIdx.x;
    int node = gid / TPN, oct = gid % TPN;
    if (node >= n) return;
    float dn = dinv[node];
    int e0 = row_ptr[node], e1 = row_ptr[node + 1];
    float acc[8];
    {   // self term: h'[node]
        uint4 v = *reinterpret_cast<const uint4*>(&h[(size_t)node * LD + oct * 8]);
        unpack2(v.x, acc[0], acc[1]);
        unpack2(v.y, acc[2], acc[3]);
        unpack2(v.z, acc[4], acc[5]);
        unpack2(v.w, acc[6], acc[7]);
    }
    for (int e = e0; e < e1; ++e) {
        int s = csr_src[e];
        uint4 v = *reinterpret_cast<const uint4*>(&h[(size_t)s * LD + oct * 8]);
        float a, b;
        unpack2(v.x, a, b); acc[0] += a; acc[1] += b;
        unpack2(v.y, a, b); acc[2] += a; acc[3] += b;
        unpack2(v.z, a, b); acc[4] += a; acc[5] += b;
        unpack2(v.w, a, b); acc[6] += a; acc[7] += b;
    }
    uint4 o;
    o.x = (uint)f2bs(acc[0] * dn) | ((uint)f2bs(acc[1] * dn) << 16);
    o.y = (uint)f2bs(acc[2] * dn) | ((uint)f2bs(acc[3] * dn) << 16);
    o.z = (uint)f2bs(acc[4] * dn) | ((uint)f2bs(acc[5] * dn) << 16);
    o.w = (uint)f2bs(acc[6] * dn) | ((uint)f2bs(acc[7] * dn) << 16);
    *reinterpret_cast<uint4*>(&agg[(size_t)node * LD + oct * 8]) = o;
}

// ---------------- bf16 MFMA GEMM: C = A @ Wt^T (+bias+relu)(*rowscale), bf16 out ----------------
template <int KI, int LDA, int KO, int LDC, int NBY, bool SCALEROW>
__global__ __launch_bounds__(256) void gemm_mfma(const ushort* __restrict__ A,
                                                 const ushort* __restrict__ Bt,
                                                 const float* __restrict__ bias,
                                                 const float* __restrict__ rowscale,
                                                 ushort* __restrict__ C, int n) {
    __shared__ ushort sA[64][40];
    __shared__ ushort sB[64][40];
    const int t = threadIdx.x;
    const int row0 = (blockIdx.x / NBY) * 64;
    const int col0 = (blockIdx.x % NBY) * 64;
    const int wid = t >> 6, lane = t & 63;
    const int wr = wid >> 1, wc = wid & 1;
    const int lrow = lane & 15;
    const int kgrp = lane >> 4;
    const int srr = t >> 2;      // staging row 0..63
    const int skq = t & 3;       // staging k-octet
    f32x4 acc[2][2];
#pragma unroll
    for (int i = 0; i < 2; ++i)
#pragma unroll
        for (int j = 0; j < 2; ++j) acc[i][j] = (f32x4)0.f;

    const int nk = (KI + 31) / 32;
    for (int ks = 0; ks < nk; ++ks) {
        const int kbase = ks * 32 + skq * 8;
        {   // stage A tile (64 rows x 32 k)
            int grow = row0 + srr;
            uint4 v = {0, 0, 0, 0};
            if (grow < n && kbase < LDA)
                v = *reinterpret_cast<const uint4*>(&A[(size_t)grow * LDA + kbase]);
            *reinterpret_cast<uint4*>(&sA[srr][skq * 8]) = v;
        }
        {   // stage B tile (64 cols x 32 k)
            int gcol = col0 + srr;
            uint4 v = {0, 0, 0, 0};
            if (gcol < KO && kbase < LDA)
                v = *reinterpret_cast<const uint4*>(&Bt[(size_t)gcol * LDA + kbase]);
            *reinterpret_cast<uint4*>(&sB[srr][skq * 8]) = v;
        }
        __syncthreads();
        s16x8 a0 = *reinterpret_cast<const s16x8*>(&sA[wr * 32 + lrow][kgrp * 8]);
        s16x8 a1 = *reinterpret_cast<const s16x8*>(&sA[wr * 32 + 16 + lrow][kgrp * 8]);
        s16x8 b0 = *reinterpret_cast<const s16x8*>(&sB[wc * 32 + lrow][kgrp * 8]);
        s16x8 b1 = *reinterpret_cast<const s16x8*>(&sB[wc * 32 + 16 + lrow][kgrp * 8]);
        acc[0][0] = __builtin_amdgcn_mfma_f32_16x16x32_bf16(a0, b0, acc[0][0], 0, 0, 0);
        acc[0][1] = __builtin_amdgcn_mfma_f32_16x16x32_bf16(a0, b1, acc[0][1], 0, 0, 0);
        acc[1][0] = __builtin_amdgcn_mfma_f32_16x16x32_bf16(a1, b0, acc[1][0], 0, 0, 0);
        acc[1][1] = __builtin_amdgcn_mfma_f32_16x16x32_bf16(a1, b1, acc[1][1], 0, 0, 0);
        __syncthreads();
    }
#pragma unroll
    for (int fr = 0; fr < 2; ++fr)
#pragma unroll
        for (int fc = 0; fc < 2; ++fc)
#pragma unroll
            for (int r = 0; r < 4; ++r) {
                int row = row0 + wr * 32 + fr * 16 + kgrp * 4 + r;
                int col = col0 + wc * 32 + fc * 16 + lrow;
                if (row < n && col < LDC) {
                    float v = acc[fr][fc][r];
                    ushort o = 0;
                    if (col < KO) {
                        v = fmaxf(v + bias[col], 0.f);
                        if (SCALEROW) v *= rowscale[row];
                        o = f2bs(v);
                    }
                    C[(size_t)row * LDC + col] = o;
                }
            }
}

// ---------------- layer-3 MFMA GEMM with FUSED segment-max pool ----------------
// Computes relu(agg @ Wt3^T + b3) tile in LDS (bf16-rounded, bit-identical to old h3),
// then per-column segmented max over the sorted batch -> atomicMax into g0 (uint bits,
// valid since values >= 0; max is order-independent -> deterministic). h3 never hits HBM.
__global__ __launch_bounds__(256) void gemm_mfma_segmax(const ushort* __restrict__ A,
                                                        const ushort* __restrict__ Bt,
                                                        const float* __restrict__ bias,
                                                        const int* __restrict__ batch,
                                                        uint* __restrict__ g0u, int n) {
    constexpr int KI = 156, LDA = 160, KO = 312, NBY = 5;
    __shared__ ushort sA[64][40];
    __shared__ ushort sB[64][40];
    __shared__ ushort sC[64][66];
    __shared__ int sbatch[64];
    const int t = threadIdx.x;
    const int row0 = (blockIdx.x / NBY) * 64;
    const int col0 = (blockIdx.x % NBY) * 64;
    const int wid = t >> 6, lane = t & 63;
    const int wr = wid >> 1, wc = wid & 1;
    const int lrow = lane & 15;
    const int kgrp = lane >> 4;
    const int srr = t >> 2;
    const int skq = t & 3;
    if (t < 64) sbatch[t] = (row0 + t < n) ? batch[row0 + t] : -1;
    f32x4 acc[2][2];
#pragma unroll
    for (int i = 0; i < 2; ++i)
#pragma unroll
        for (int j = 0; j < 2; ++j) acc[i][j] = (f32x4)0.f;

    const int nk = (KI + 31) / 32;
    for (int ks = 0; ks < nk; ++ks) {
        const int kbase = ks * 32 + skq * 8;
        {
            int grow = row0 + srr;
            uint4 v = {0, 0, 0, 0};
            if (grow < n && kbase < LDA)
                v = *reinterpret_cast<const uint4*>(&A[(size_t)grow * LDA + kbase]);
            *reinterpret_cast<uint4*>(&sA[srr][skq * 8]) = v;
        }
        {
            int gcol = col0 + srr;
            uint4 v = {0, 0, 0, 0};
            if (gcol < KO && kbase < LDA)
                v = *reinterpret_cast<const uint4*>(&Bt[(size_t)gcol * LDA + kbase]);
            *reinterpret_cast<uint4*>(&sB[srr][skq * 8]) = v;
        }
        __syncthreads();
        s16x8 a0 = *reinterpret_cast<const s16x8*>(&sA[wr * 32 + lrow][kgrp * 8]);
        s16x8 a1 = *reinterpret_cast<const s16x8*>(&sA[wr * 32 + 16 + lrow][kgrp * 8]);
        s16x8 b0 = *reinterpret_cast<const s16x8*>(&sB[wc * 32 + lrow][kgrp * 8]);
        s16x8 b1 = *reinterpret_cast<const s16x8*>(&sB[wc * 32 + 16 + lrow][kgrp * 8]);
        acc[0][0] = __builtin_amdgcn_mfma_f32_16x16x32_bf16(a0, b0, acc[0][0], 0, 0, 0);
        acc[0][1] = __builtin_amdgcn_mfma_f32_16x16x32_bf16(a0, b1, acc[0][1], 0, 0, 0);
        acc[1][0] = __builtin_amdgcn_mfma_f32_16x16x32_bf16(a1, b0, acc[1][0], 0, 0, 0);
        acc[1][1] = __builtin_amdgcn_mfma_f32_16x16x32_bf16(a1, b1, acc[1][1], 0, 0, 0);
        __syncthreads();
    }
    // stage bf16-rounded outputs to LDS (same rounding as the old h3 store)
#pragma unroll
    for (int fr = 0; fr < 2; ++fr)
#pragma unroll
        for (int fc = 0; fc < 2; ++fc)
#pragma unroll
            for (int r = 0; r < 4; ++r) {
                int lr = wr * 32 + fr * 16 + kgrp * 4 + r;
                int lc = wc * 32 + fc * 16 + lrow;
                int gcol = col0 + lc;
                ushort o = 0;
                if (gcol < KO) o = f2bs(fmaxf(acc[fr][fc][r] + bias[gcol], 0.f));
                sC[lr][lc] = o;
            }
    __syncthreads();
    // per-column segmented max over 16-row chunk (batch sorted); flush via atomicMax
    {
        int col = t & 63, q = t >> 6;
        int gcol = col0 + col;
        if (gcol < KO) {
            int base = q * 16;
            int cur = sbatch[base];
            float m = 0.f;
#pragma unroll 4
            for (int i = 0; i < 16; ++i) {
                int b = sbatch[base + i];
                if (b != cur) {
                    if (cur >= 0) atomicMax(&g0u[(size_t)cur * KO + gcol], __float_as_uint(m));
                    m = 0.f;
                    cur = b;
                }
                m = fmaxf(m, b2f(sC[base + i][col]));
            }
            if (cur >= 0) atomicMax(&g0u[(size_t)cur * KO + gcol], __float_as_uint(m));
        }
    }
}

// ---------------- head GEMM: K-split, 32x64 tile, fp32 partials ----------------
template <int KI, int KO, int KS>
__global__ __launch_bounds__(256) void gemm_head(const float* __restrict__ A,
                                                 const float* __restrict__ W,
                                                 float* __restrict__ partial, int n) {
    __shared__ float sA[16][34];
    __shared__ float sW[16][68];
    const int t = threadIdx.x;
    const int row0 = blockIdx.x * 32;
    const int col0 = blockIdx.y * 64;
    const int z = blockIdx.z;
    const int kbeg = z * KS;
    const int kend = min(KI, kbeg + KS);
    const int r0 = (t >> 4) * 2;   // 0..30 (even)
    const int c0 = (t & 15) * 4;   // 0..60 (quad)
    float acc[2][4] = {};
    for (int k0 = kbeg; k0 < kend; k0 += 16) {
        {   // stage A: 32 rows x 16 k
            int row = t >> 3, kk = (t & 7) * 2;
            int grow = row0 + row;
#pragma unroll
            for (int j = 0; j < 2; ++j) {
                float v = 0.f;
                if (grow < n && (k0 + kk + j) < kend) v = A[(size_t)grow * KI + k0 + kk + j];
                sA[kk + j][row] = v;
            }
        }
        {   // stage W: 16 k x 64 cols
            int kk = t >> 4, cc = (t & 15) * 4;
#pragma unroll
            for (int j = 0; j < 4; ++j) {
                float v = 0.f;
                if ((k0 + kk) < kend) v = W[(size_t)(k0 + kk) * KO + col0 + cc + j];
                sW[kk][cc + j] = v;
            }
        }
        __syncthreads();
#pragma unroll 8
        for (int k = 0; k < 16; ++k) {
            float2 a = *reinterpret_cast<const float2*>(&sA[k][r0]);
            float4 w = *reinterpret_cast<const float4*>(&sW[k][c0]);
            acc[0][0] = fmaf(a.x, w.x, acc[0][0]); acc[0][1] = fmaf(a.x, w.y, acc[0][1]);
            acc[0][2] = fmaf(a.x, w.z, acc[0][2]); acc[0][3] = fmaf(a.x, w.w, acc[0][3]);
            acc[1][0] = fmaf(a.y, w.x, acc[1][0]); acc[1][1] = fmaf(a.y, w.y, acc[1][1]);
            acc[1][2] = fmaf(a.y, w.z, acc[1][2]); acc[1][3] = fmaf(a.y, w.w, acc[1][3]);
        }
        __syncthreads();
    }
#pragma unroll
    for (int ri = 0; ri < 2; ++ri) {
        int row = row0 + r0 + ri;
        if (row >= n) continue;
        *reinterpret_cast<float4*>(&partial[((size_t)z * n + row) * KO + col0 + c0]) =
            make_float4(acc[ri][0], acc[ri][1], acc[ri][2], acc[ri][3]);
    }
}

// sum partials over splits + bias (+relu), scatter into C[row*ldc + col_off + col]
template <int NS, bool RELU>
__global__ void head_reduce(const float* __restrict__ partial, const float* __restrict__ bias,
                            float* __restrict__ C, int n, int KO, int ldc, int col_off) {
    int j = blockIdx.x * blockDim.x + threadIdx.x;
    if (j >= n * KO) return;
    int row = j / KO, col = j % KO;
    float acc = bias[col];
#pragma unroll
    for (int s = 0; s < NS; ++s) acc += partial[((size_t)s * n + row) * KO + col];
    if (RELU) acc = fmaxf(acc, 0.f);
    C[(size_t)row * ldc + col_off + col] = acc;
}

// ---------------- Conv1d as implicit GEMM via MFMA (bf16), K-split ----------------
__global__ __launch_bounds__(256) void conv_mfma(const float* __restrict__ T,
                                                 const ushort* __restrict__ Kbf,
                                                 float* __restrict__ partial) {
    __shared__ ushort sA[64][40];
    __shared__ ushort sB[32][40];
    const int t = threadIdx.x;
    const int row0 = blockIdx.x * 64;
    const int split = blockIdx.y;
    const int kbeg = split * CONV_KCHUNK;
    const int kend = min(6000, kbeg + CONV_KCHUNK);
    const int wid = t >> 6, lane = t & 63;
    const int lrow = lane & 15, kgrp = lane >> 4;
    f32x4 acc0 = (f32x4)0.f, acc1 = (f32x4)0.f;
    for (int k0 = kbeg; k0 < kend; k0 += 32) {
        {   // stage A (64 rows x 32 k): load fp32 T, convert to bf16 (kb multiple of 8)
            int rr = t >> 2, kq = t & 3;
            int grow = row0 + rr;                 // < 6144 always
            int b = grow / 12, h = grow % 12;
            int kb = k0 + kq * 8;
            int i = kb >> 3;
            const float* tp = &T[(size_t)b * 14250 + (size_t)i * 19 + h];
            ushort u[8];
#pragma unroll
            for (int j = 0; j < 8; ++j)
                u[j] = (kb + j < kend) ? f2bs(tp[j]) : (ushort)0;
            uint4 v;
            v.x = (uint)u[0] | ((uint)u[1] << 16);
            v.y = (uint)u[2] | ((uint)u[3] << 16);
            v.z = (uint)u[4] | ((uint)u[5] << 16);
            v.w = (uint)u[6] | ((uint)u[7] << 16);
            *reinterpret_cast<uint4*>(&sA[rr][kq * 8]) = v;
        }
        if (t < 128) {   // stage B (32 outs x 32 k) from padded Kbf
            int o = t >> 2, kq = t & 3;
            uint4 v = *reinterpret_cast<const uint4*>(&Kbf[(size_t)o * 6016 + k0 + kq * 8]);
            *reinterpret_cast<uint4*>(&sB[o][kq * 8]) = v;
        }
        __syncthreads();
        s16x8 a0 = *reinterpret_cast<const s16x8*>(&sA[wid * 16 + lrow][kgrp * 8]);
        s16x8 b0 = *reinterpret_cast<const s16x8*>(&sB[lrow][kgrp * 8]);
        s16x8 b1 = *reinterpret_cast<const s16x8*>(&sB[16 + lrow][kgrp * 8]);
        acc0 = __builtin_amdgcn_mfma_f32_16x16x32_bf16(a0, b0, acc0, 0, 0, 0);
        acc1 = __builtin_amdgcn_mfma_f32_16x16x32_bf16(a0, b1, acc1, 0, 0, 0);
        __syncthreads();
    }
#pragma unroll
    for (int r = 0; r < 4; ++r) {
        int row = row0 + wid * 16 + kgrp * 4 + r;   // C/D: row=(lane>>4)*4+reg, col=lane&15
        int b = row / 12, h = row % 12;
        partial[(((size_t)split * NBATCH + b) * 32 + lrow) * 12 + h] = acc0[r];
        partial[(((size_t)split * NBATCH + b) * 32 + (16 + lrow)) * 12 + h] = acc1[r];
    }
}

__global__ void conv_reduce(const float* __restrict__ partial, const float* __restrict__ bxt,
                            float* __restrict__ convb) {
    int j = blockIdx.x * blockDim.x + threadIdx.x;
    if (j >= NBATCH * 384) return;
    int b = j / 384, rem = j % 384;
    int o = rem / 12, h = rem % 12;
    float acc = bxt[o];
#pragma unroll
    for (int s = 0; s < CONV_KSPLIT; ++s)
        acc += partial[(((size_t)s * NBATCH + b) * 32 + o) * 12 + h];
    convb[j] = acc;
}

// ---------------- final [512,512] @ [512,1] ----------------
__global__ void final_out(const float* __restrict__ f2, const float* __restrict__ Wo,
                          const float* __restrict__ bo, float* __restrict__ out) {
    int row = blockIdx.x * (blockDim.x / 64) + (threadIdx.x / 64);
    int lane = threadIdx.x & 63;
    if (row >= NBATCH) return;
    float acc = 0.f;
    for (int k = lane; k < 512; k += 64) acc = fmaf(f2[(size_t)row * 512 + k], Wo[k], acc);
#pragma unroll
    for (int off = 32; off > 0; off >>= 1) acc += __shfl_down(acc, off);
    if (lane == 0) out[row] = acc + bo[0];
}

extern "C" void kernel_launch(void* const* d_in, const int* in_sizes, int n_in,
                              void* d_out, int out_size, void* d_ws, size_t ws_size,
                              hipStream_t stream) {
    (void)in_sizes; (void)n_in; (void)out_size; (void)ws_size;
    const float* x     = (const float*)d_in[0];
    const int*   ei    = (const int*)d_in[1];
    const int*   batch = (const int*)d_in[2];
    const float* T     = (const float*)d_in[3];
    const float* W1 = (const float*)d_in[4];   const float* b1 = (const float*)d_in[5];
    const float* W2 = (const float*)d_in[6];   const float* b2 = (const float*)d_in[7];
    const float* W3 = (const float*)d_in[8];   const float* b3 = (const float*)d_in[9];
    const float* Wg1 = (const float*)d_in[10]; const float* bg1 = (const float*)d_in[11];
    const float* Wg2 = (const float*)d_in[12]; const float* bg2 = (const float*)d_in[13];
    const float* Kxt = (const float*)d_in[14]; const float* bxt = (const float*)d_in[15];
    const float* Wxt = (const float*)d_in[16]; const float* bxt2 = (const float*)d_in[17];
    const float* Wf1 = (const float*)d_in[18]; const float* bf1 = (const float*)d_in[19];
    const float* Wf2 = (const float*)d_in[20]; const float* bf2 = (const float*)d_in[21];
    const float* Wo = (const float*)d_in[22];  const float* bo = (const float*)d_in[23];
    const int* src = ei;
    const int* dst = ei + N_EDGESC;

    char* ws = (char*)d_ws;
    size_t off = 0;
    auto alloc = [&](size_t bytes) -> void* {
        void* p = ws + off;
        off += (bytes + 255) & ~(size_t)255;
        return p;
    };
    int*   deg      = (int*)alloc((size_t)N_NODESC * 4);
    float* dinv     = (float*)alloc((size_t)N_NODESC * 4);
    int*   row_ptr  = (int*)alloc((size_t)(N_NODESC + 1) * 4);
    int*   fillc    = (int*)alloc((size_t)N_NODESC * 4);
    int*   csr_src  = (int*)alloc((size_t)N_EDGESC * 4);
    int*   csums    = (int*)alloc((size_t)4096 * 4);
    float* g0       = (float*)alloc((size_t)NBATCH * 312 * 4);
    float* g1       = (float*)alloc((size_t)NBATCH * 1024 * 4);
    float* convb    = (float*)alloc((size_t)NBATCH * 384 * 4);
    float* xc       = (float*)alloc((size_t)NBATCH * 256 * 4);
    float* f1       = (float*)alloc((size_t)NBATCH * 1024 * 4);
    float* f2       = (float*)alloc((size_t)NBATCH * 512 * 4);
    float* cpart    = (float*)alloc((size_t)CONV_KSPLIT * NBATCH * 32 * 12 * 4);
    float* hpart    = (float*)alloc((size_t)8 * NBATCH * 128 * 4);
    ushort* xbf     = (ushort*)alloc((size_t)N_NODESC * 80 * 2);   // x' (80) -> later h1' (80)
    ushort* aggbuf  = (ushort*)alloc((size_t)N_NODESC * 160 * 2);  // agg1/2 (80), agg3 (160)
    ushort* hbuf    = (ushort*)alloc((size_t)N_NODESC * 160 * 2);  // h2' (160)
    ushort* Wt1     = (ushort*)alloc((size_t)78 * 80 * 2);
    ushort* Wt2     = (ushort*)alloc((size_t)156 * 80 * 2);
    ushort* Wt3     = (ushort*)alloc((size_t)312 * 160 * 2);
    ushort* Kbf     = (ushort*)alloc((size_t)32 * 6016 * 2);
    float* out      = (float*)d_out;

    const int TPB = 256;

    // ---- graph structure ----
    zero_ints<<<divup(N_NODESC, TPB), TPB, 0, stream>>>(deg, N_NODESC);
    count_deg<<<divup(N_EDGESC, TPB), TPB, 0, stream>>>(dst, deg, N_EDGESC);
    compute_dinv<<<divup(N_NODESC, TPB), TPB, 0, stream>>>(deg, dinv, N_NODESC);
    int nchunks = divup(N_NODESC, SCAN_CHUNK);
    scan_chunks<<<nchunks, 256, 0, stream>>>(deg, row_ptr, csums, N_NODESC);
    scan_sums<<<1, 64, 0, stream>>>(csums, nchunks);
    finalize_rowptr<<<divup(N_NODESC, TPB), TPB, 0, stream>>>(row_ptr, csums, fillc, N_NODESC, N_EDGESC);
    fill_csr<<<divup(N_EDGESC, TPB), TPB, 0, stream>>>(src, dst, fillc, csr_src, N_EDGESC);

    // ---- bf16 conversions (x folded with dinv) ----
    convert_x_bf16<<<divup(N_NODESC * 80, TPB), TPB, 0, stream>>>(x, dinv, xbf, N_NODESC, 78, 80);
    transpose_w_bf16<<<divup(78 * 80, TPB), TPB, 0, stream>>>(W1, Wt1, 78, 78, 80);
    transpose_w_bf16<<<divup(156 * 80, TPB), TPB, 0, stream>>>(W2, Wt2, 78, 156, 80);
    transpose_w_bf16<<<divup(312 * 160, TPB), TPB, 0, stream>>>(W3, Wt3, 156, 312, 160);
    convert_k_bf16<<<divup(32 * 6016, TPB), TPB, 0, stream>>>(Kxt, Kbf);

    // ---- GCN layer 1: agg(x') -> gemm(+bias+relu, *dinv) -> h1' (LD 80) ----
    gcn_gather_vec<80><<<divup(N_NODESC * 10, TPB), TPB, 0, stream>>>(
        xbf, row_ptr, csr_src, dinv, aggbuf, N_NODESC);
    gemm_mfma<78, 80, 78, 80, 2, true><<<divup(N_NODESC, 64) * 2, 256, 0, stream>>>(
        aggbuf, Wt1, b1, dinv, xbf, N_NODESC);   // h1' overwrites xbf

    // ---- GCN layer 2: agg(h1') -> gemm(*dinv) -> h2' (LD 160) ----
    gcn_gather_vec<80><<<divup(N_NODESC * 10, TPB), TPB, 0, stream>>>(
        xbf, row_ptr, csr_src, dinv, aggbuf, N_NODESC);
    gemm_mfma<78, 80, 156, 160, 3, true><<<divup(N_NODESC, 64) * 3, 256, 0, stream>>>(
        aggbuf, Wt2, b2, dinv, hbuf, N_NODESC);

    // ---- GCN layer 3: agg(h2') -> gemm + FUSED segment-max -> g0 (h3 never materialized) ----
    gcn_gather_vec<160><<<divup(N_NODESC * 20, TPB), TPB, 0, stream>>>(
        hbuf, row_ptr, csr_src, dinv, aggbuf, N_NODESC);
    zero_ints<<<divup(NBATCH * 312, TPB), TPB, 0, stream>>>((int*)g0, NBATCH * 312);
    gemm_mfma_segmax<<<divup(N_NODESC, 64) * 5, 256, 0, stream>>>(
        aggbuf, Wt3, b3, batch, (uint*)g0, N_NODESC);

    // ---- graph head: g1 = relu(g0 @ Wg1 + bg1) ----
    gemm_head<312, 1024, 312><<<dim3(16, 16, 1), 256, 0, stream>>>(g0, Wg1, hpart, NBATCH);
    head_reduce<1, true><<<divup(NBATCH * 1024, TPB), TPB, 0, stream>>>(
        hpart, bg1, g1, NBATCH, 1024, 1024, 0);
    // xc[:, :128] = g1 @ Wg2 + bg2
    gemm_head<1024, 128, 128><<<dim3(16, 2, 8), 256, 0, stream>>>(g1, Wg2, hpart, NBATCH);
    head_reduce<8, false><<<divup(NBATCH * 128, TPB), TPB, 0, stream>>>(
        hpart, bg2, xc, NBATCH, 128, 256, 0);

    // ---- protein branch: implicit-GEMM conv via MFMA ----
    conv_mfma<<<dim3(6144 / 64, CONV_KSPLIT), 256, 0, stream>>>(T, Kbf, cpart);
    conv_reduce<<<divup(NBATCH * 384, TPB), TPB, 0, stream>>>(cpart, bxt, convb);
    // xc[:, 128:] = convb @ Wxt + bxt2
    gemm_head<384, 128, 48><<<dim3(16, 2, 8), 256, 0, stream>>>(convb, Wxt, hpart, NBATCH);
    head_reduce<8, false><<<divup(NBATCH * 128, TPB), TPB, 0, stream>>>(
        hpart, bxt2, xc, NBATCH, 128, 256, 128);

    // ---- fusion MLP ----
    gemm_head<256, 1024, 256><<<dim3(16, 16, 1), 256, 0, stream>>>(xc, Wf1, hpart, NBATCH);
    head_reduce<1, true><<<divup(NBATCH * 1024, TPB), TPB, 0, stream>>>(
        hpart, bf1, f1, NBATCH, 1024, 1024, 0);
    gemm_head<1024, 512, 512><<<dim3(16, 8, 2), 256, 0, stream>>>(f1, Wf2, hpart, NBATCH);
    head_reduce<2, true><<<divup(NBATCH * 512, TPB), TPB, 0, stream>>>(
        hpart, bf2, f2, NBATCH, 512, 512, 0);
    final_out<<<divup(NBATCH, 4), 256, 0, stream>>>(f2, Wo, bo, out);
}

// Round 15
// 389.209 us; speedup vs baseline: 1.4049x; 1.1408x over previous
//
#include <hip/hip_runtime.h>
#include <hip/hip_bf16.h>
#include <cstddef>
#include <cstdint>

#define N_NODESC 100000
#define N_EDGESC 500000
#define NBATCH   512
#define SCAN_CHUNK 1024
#define CONV_KSPLIT 16
#define CONV_KCHUNK 384    // multiple of 32 -> k-octets stay channel-aligned; last split ragged (240)

static inline int divup(int a, int b) { return (a + b - 1) / b; }

typedef __hip_bfloat16 bf16;
typedef short s16x8 __attribute__((ext_vector_type(8)));
typedef float f32x4 __attribute__((ext_vector_type(4)));

__device__ inline float b2f(ushort u) {
    union { uint i; float f; } c; c.i = (uint)u << 16; return c.f;
}
__device__ inline ushort f2bs(float v) {
    bf16 b = __float2bfloat16(v);
    return *reinterpret_cast<ushort*>(&b);
}
__device__ inline void unpack2(uint u, float& a, float& b) {
    union { uint i; float f; } lo, hi;
    lo.i = u << 16; hi.i = u & 0xffff0000u;
    a = lo.f; b = hi.f;
}

// ---------------- zero ints ----------------
__global__ void zero_ints(int* __restrict__ p, int n) {
    int i = blockIdx.x * blockDim.x + threadIdx.x;
    if (i < n) p[i] = 0;
}

// ---------------- degree / dinv ----------------
__global__ void count_deg(const int* __restrict__ dst, int* __restrict__ deg, int e) {
    int i = blockIdx.x * blockDim.x + threadIdx.x;
    if (i < e) atomicAdd(&deg[dst[i]], 1);
}

__global__ void compute_dinv(const int* __restrict__ deg, float* __restrict__ dinv, int n) {
    int i = blockIdx.x * blockDim.x + threadIdx.x;
    if (i < n) dinv[i] = 1.0f / sqrtf((float)deg[i] + 1.0f);
}

// ---------------- exclusive scan (3-phase) ----------------
__global__ void scan_chunks(const int* __restrict__ deg, int* __restrict__ out,
                            int* __restrict__ sums, int n) {
    __shared__ int sdata[256];
    int t = threadIdx.x;
    int base = blockIdx.x * SCAN_CHUNK;
    int v[4];
    int s = 0;
#pragma unroll
    for (int j = 0; j < 4; ++j) {
        int idx = base + t * 4 + j;
        v[j] = s;
        int d = (idx < n) ? deg[idx] : 0;
        s += d;
    }
    int x = s;
    sdata[t] = x;
    __syncthreads();
    for (int off = 1; off < 256; off <<= 1) {
        int y = (t >= off) ? sdata[t - off] : 0;
        __syncthreads();
        x += y;
        sdata[t] = x;
        __syncthreads();
    }
    int thread_excl = x - s;
    if (t == 255) sums[blockIdx.x] = x;
#pragma unroll
    for (int j = 0; j < 4; ++j) {
        int idx = base + t * 4 + j;
        if (idx < n) out[idx] = thread_excl + v[j];
    }
}

__global__ void scan_sums(int* sums, int nchunks) {
    if (threadIdx.x == 0 && blockIdx.x == 0) {
        int acc = 0;
        for (int i = 0; i < nchunks; ++i) { int v = sums[i]; sums[i] = acc; acc += v; }
    }
}

__global__ void finalize_rowptr(int* __restrict__ row_ptr, const int* __restrict__ sums,
                                int* __restrict__ fill, int n, int e) {
    int i = blockIdx.x * blockDim.x + threadIdx.x;
    if (i < n) {
        int v = row_ptr[i] + sums[i / SCAN_CHUNK];
        row_ptr[i] = v;
        fill[i] = v;
    }
    if (i == 0) row_ptr[n] = e;
}

__global__ void fill_csr(const int* __restrict__ src, const int* __restrict__ dst,
                         int* __restrict__ fill, int* __restrict__ csr_src, int e) {
    int i = blockIdx.x * blockDim.x + threadIdx.x;
    if (i < e) {
        int d = dst[i];
        int pos = atomicAdd(&fill[d], 1);
        csr_src[pos] = src[i];
    }
}

// ---------------- fp32 -> bf16 node features, scaled by dinv[node], padded stride ----------------
__global__ void convert_x_bf16(const float* __restrict__ x, const float* __restrict__ dinv,
                               ushort* __restrict__ xbf, int n, int ki, int ld) {
    int i = blockIdx.x * blockDim.x + threadIdx.x;
    int total = n * ld;
    if (i >= total) return;
    int node = i / ld, col = i % ld;
    xbf[i] = (col < ki) ? f2bs(x[(size_t)node * ki + col] * dinv[node]) : (ushort)0;
}

// ---------------- W[KI,KO] fp32 -> Wt[KO,LD] bf16 (transposed, zero-padded) ----------------
__global__ void transpose_w_bf16(const float* __restrict__ W, ushort* __restrict__ Wt,
                                 int ki, int ko, int ld) {
    int i = blockIdx.x * blockDim.x + threadIdx.x;
    int total = ko * ld;
    if (i >= total) return;
    int o = i / ld, k = i % ld;
    Wt[i] = (k < ki) ? f2bs(W[(size_t)k * ko + o]) : (ushort)0;
}

// ---------------- Kxt[32][6000] fp32 -> Kbf[32][6016] bf16 (zero-padded) ----------------
__global__ void convert_k_bf16(const float* __restrict__ Kxt, ushort* __restrict__ Kbf) {
    int i = blockIdx.x * blockDim.x + threadIdx.x;
    if (i >= 32 * 6016) return;
    int o = i / 6016, k = i % 6016;
    Kbf[i] = (k < 6000) ? f2bs(Kxt[(size_t)o * 6000 + k]) : (ushort)0;
}

// ---------------- vectorized GCN aggregation on dinv-prescaled features ----------------
template <int LD>
__global__ void gcn_gather_vec(const ushort* __restrict__ h, const int* __restrict__ row_ptr,
                               const int* __restrict__ csr_src, const float* __restrict__ dinv,
                               ushort* __restrict__ agg, int n) {
    constexpr int TPN = LD / 8;
    int gid = blockIdx.x * blockDim.x + threadIdx.x;
    int node = gid / TPN, oct = gid % TPN;
    if (node >= n) return;
    float dn = dinv[node];
    int e0 = row_ptr[node], e1 = row_ptr[node + 1];
    float acc[8];
    {   // self term: h'[node]
        uint4 v = *reinterpret_cast<const uint4*>(&h[(size_t)node * LD + oct * 8]);
        unpack2(v.x, acc[0], acc[1]);
        unpack2(v.y, acc[2], acc[3]);
        unpack2(v.z, acc[4], acc[5]);
        unpack2(v.w, acc[6], acc[7]);
    }
    for (int e = e0; e < e1; ++e) {
        int s = csr_src[e];
        uint4 v = *reinterpret_cast<const uint4*>(&h[(size_t)s * LD + oct * 8]);
        float a, b;
        unpack2(v.x, a, b); acc[0] += a; acc[1] += b;
        unpack2(v.y, a, b); acc[2] += a; acc[3] += b;
        unpack2(v.z, a, b); acc[4] += a; acc[5] += b;
        unpack2(v.w, a, b); acc[6] += a; acc[7] += b;
    }
    uint4 o;
    o.x = (uint)f2bs(acc[0] * dn) | ((uint)f2bs(acc[1] * dn) << 16);
    o.y = (uint)f2bs(acc[2] * dn) | ((uint)f2bs(acc[3] * dn) << 16);
    o.z = (uint)f2bs(acc[4] * dn) | ((uint)f2bs(acc[5] * dn) << 16);
    o.w = (uint)f2bs(acc[6] * dn) | ((uint)f2bs(acc[7] * dn) << 16);
    *reinterpret_cast<uint4*>(&agg[(size_t)node * LD + oct * 8]) = o;
}

// ---------------- bf16 MFMA GEMM: C = A @ Wt^T (+bias+relu)(*rowscale), bf16 out ----------------
template <int KI, int LDA, int KO, int LDC, int NBY, bool SCALEROW>
__global__ __launch_bounds__(256) void gemm_mfma(const ushort* __restrict__ A,
                                                 const ushort* __restrict__ Bt,
                                                 const float* __restrict__ bias,
                                                 const float* __restrict__ rowscale,
                                                 ushort* __restrict__ C, int n) {
    __shared__ ushort sA[64][40];
    __shared__ ushort sB[64][40];
    const int t = threadIdx.x;
    const int row0 = (blockIdx.x / NBY) * 64;
    const int col0 = (blockIdx.x % NBY) * 64;
    const int wid = t >> 6, lane = t & 63;
    const int wr = wid >> 1, wc = wid & 1;
    const int lrow = lane & 15;
    const int kgrp = lane >> 4;
    const int srr = t >> 2;      // staging row 0..63
    const int skq = t & 3;       // staging k-octet
    f32x4 acc[2][2];
#pragma unroll
    for (int i = 0; i < 2; ++i)
#pragma unroll
        for (int j = 0; j < 2; ++j) acc[i][j] = (f32x4)0.f;

    const int nk = (KI + 31) / 32;
    for (int ks = 0; ks < nk; ++ks) {
        const int kbase = ks * 32 + skq * 8;
        {   // stage A tile (64 rows x 32 k)
            int grow = row0 + srr;
            uint4 v = {0, 0, 0, 0};
            if (grow < n && kbase < LDA)
                v = *reinterpret_cast<const uint4*>(&A[(size_t)grow * LDA + kbase]);
            *reinterpret_cast<uint4*>(&sA[srr][skq * 8]) = v;
        }
        {   // stage B tile (64 cols x 32 k)
            int gcol = col0 + srr;
            uint4 v = {0, 0, 0, 0};
            if (gcol < KO && kbase < LDA)
                v = *reinterpret_cast<const uint4*>(&Bt[(size_t)gcol * LDA + kbase]);
            *reinterpret_cast<uint4*>(&sB[srr][skq * 8]) = v;
        }
        __syncthreads();
        s16x8 a0 = *reinterpret_cast<const s16x8*>(&sA[wr * 32 + lrow][kgrp * 8]);
        s16x8 a1 = *reinterpret_cast<const s16x8*>(&sA[wr * 32 + 16 + lrow][kgrp * 8]);
        s16x8 b0 = *reinterpret_cast<const s16x8*>(&sB[wc * 32 + lrow][kgrp * 8]);
        s16x8 b1 = *reinterpret_cast<const s16x8*>(&sB[wc * 32 + 16 + lrow][kgrp * 8]);
        acc[0][0] = __builtin_amdgcn_mfma_f32_16x16x32_bf16(a0, b0, acc[0][0], 0, 0, 0);
        acc[0][1] = __builtin_amdgcn_mfma_f32_16x16x32_bf16(a0, b1, acc[0][1], 0, 0, 0);
        acc[1][0] = __builtin_amdgcn_mfma_f32_16x16x32_bf16(a1, b0, acc[1][0], 0, 0, 0);
        acc[1][1] = __builtin_amdgcn_mfma_f32_16x16x32_bf16(a1, b1, acc[1][1], 0, 0, 0);
        __syncthreads();
    }
#pragma unroll
    for (int fr = 0; fr < 2; ++fr)
#pragma unroll
        for (int fc = 0; fc < 2; ++fc)
#pragma unroll
            for (int r = 0; r < 4; ++r) {
                int row = row0 + wr * 32 + fr * 16 + kgrp * 4 + r;
                int col = col0 + wc * 32 + fc * 16 + lrow;
                if (row < n && col < LDC) {
                    float v = acc[fr][fc][r];
                    ushort o = 0;
                    if (col < KO) {
                        v = fmaxf(v + bias[col], 0.f);
                        if (SCALEROW) v *= rowscale[row];
                        o = f2bs(v);
                    }
                    C[(size_t)row * LDC + col] = o;
                }
            }
}

// ---------------- layer-3 MFMA GEMM with FUSED segment-max pool ----------------
__global__ __launch_bounds__(256) void gemm_mfma_segmax(const ushort* __restrict__ A,
                                                        const ushort* __restrict__ Bt,
                                                        const float* __restrict__ bias,
                                                        const int* __restrict__ batch,
                                                        uint* __restrict__ g0u, int n) {
    constexpr int KI = 156, LDA = 160, KO = 312, NBY = 5;
    __shared__ ushort sA[64][40];
    __shared__ ushort sB[64][40];
    __shared__ ushort sC[64][66];
    __shared__ int sbatch[64];
    const int t = threadIdx.x;
    const int row0 = (blockIdx.x / NBY) * 64;
    const int col0 = (blockIdx.x % NBY) * 64;
    const int wid = t >> 6, lane = t & 63;
    const int wr = wid >> 1, wc = wid & 1;
    const int lrow = lane & 15;
    const int kgrp = lane >> 4;
    const int srr = t >> 2;
    const int skq = t & 3;
    if (t < 64) sbatch[t] = (row0 + t < n) ? batch[row0 + t] : -1;
    f32x4 acc[2][2];
#pragma unroll
    for (int i = 0; i < 2; ++i)
#pragma unroll
        for (int j = 0; j < 2; ++j) acc[i][j] = (f32x4)0.f;

    const int nk = (KI + 31) / 32;
    for (int ks = 0; ks < nk; ++ks) {
        const int kbase = ks * 32 + skq * 8;
        {
            int grow = row0 + srr;
            uint4 v = {0, 0, 0, 0};
            if (grow < n && kbase < LDA)
                v = *reinterpret_cast<const uint4*>(&A[(size_t)grow * LDA + kbase]);
            *reinterpret_cast<uint4*>(&sA[srr][skq * 8]) = v;
        }
        {
            int gcol = col0 + srr;
            uint4 v = {0, 0, 0, 0};
            if (gcol < KO && kbase < LDA)
                v = *reinterpret_cast<const uint4*>(&Bt[(size_t)gcol * LDA + kbase]);
            *reinterpret_cast<uint4*>(&sB[srr][skq * 8]) = v;
        }
        __syncthreads();
        s16x8 a0 = *reinterpret_cast<const s16x8*>(&sA[wr * 32 + lrow][kgrp * 8]);
        s16x8 a1 = *reinterpret_cast<const s16x8*>(&sA[wr * 32 + 16 + lrow][kgrp * 8]);
        s16x8 b0 = *reinterpret_cast<const s16x8*>(&sB[wc * 32 + lrow][kgrp * 8]);
        s16x8 b1 = *reinterpret_cast<const s16x8*>(&sB[wc * 32 + 16 + lrow][kgrp * 8]);
        acc[0][0] = __builtin_amdgcn_mfma_f32_16x16x32_bf16(a0, b0, acc[0][0], 0, 0, 0);
        acc[0][1] = __builtin_amdgcn_mfma_f32_16x16x32_bf16(a0, b1, acc[0][1], 0, 0, 0);
        acc[1][0] = __builtin_amdgcn_mfma_f32_16x16x32_bf16(a1, b0, acc[1][0], 0, 0, 0);
        acc[1][1] = __builtin_amdgcn_mfma_f32_16x16x32_bf16(a1, b1, acc[1][1], 0, 0, 0);
        __syncthreads();
    }
#pragma unroll
    for (int fr = 0; fr < 2; ++fr)
#pragma unroll
        for (int fc = 0; fc < 2; ++fc)
#pragma unroll
            for (int r = 0; r < 4; ++r) {
                int lr = wr * 32 + fr * 16 + kgrp * 4 + r;
                int lc = wc * 32 + fc * 16 + lrow;
                int gcol = col0 + lc;
                ushort o = 0;
                if (gcol < KO) o = f2bs(fmaxf(acc[fr][fc][r] + bias[gcol], 0.f));
                sC[lr][lc] = o;
            }
    __syncthreads();
    {
        int col = t & 63, q = t >> 6;
        int gcol = col0 + col;
        if (gcol < KO) {
            int base = q * 16;
            int cur = sbatch[base];
            float m = 0.f;
#pragma unroll 4
            for (int i = 0; i < 16; ++i) {
                int b = sbatch[base + i];
                if (b != cur) {
                    if (cur >= 0) atomicMax(&g0u[(size_t)cur * KO + gcol], __float_as_uint(m));
                    m = 0.f;
                    cur = b;
                }
                m = fmaxf(m, b2f(sC[base + i][col]));
            }
            if (cur >= 0) atomicMax(&g0u[(size_t)cur * KO + gcol], __float_as_uint(m));
        }
    }
}

// ---------------- head GEMM: K-split, 32x64 tile, fp32 partials ----------------
template <int KI, int KO, int KS>
__global__ __launch_bounds__(256) void gemm_head(const float* __restrict__ A,
                                                 const float* __restrict__ W,
                                                 float* __restrict__ partial, int n) {
    __shared__ float sA[16][34];
    __shared__ float sW[16][68];
    const int t = threadIdx.x;
    const int row0 = blockIdx.x * 32;
    const int col0 = blockIdx.y * 64;
    const int z = blockIdx.z;
    const int kbeg = z * KS;
    const int kend = min(KI, kbeg + KS);
    const int r0 = (t >> 4) * 2;   // 0..30 (even)
    const int c0 = (t & 15) * 4;   // 0..60 (quad)
    float acc[2][4] = {};
    for (int k0 = kbeg; k0 < kend; k0 += 16) {
        {   // stage A: 32 rows x 16 k
            int row = t >> 3, kk = (t & 7) * 2;
            int grow = row0 + row;
#pragma unroll
            for (int j = 0; j < 2; ++j) {
                float v = 0.f;
                if (grow < n && (k0 + kk + j) < kend) v = A[(size_t)grow * KI + k0 + kk + j];
                sA[kk + j][row] = v;
            }
        }
        {   // stage W: 16 k x 64 cols
            int kk = t >> 4, cc = (t & 15) * 4;
#pragma unroll
            for (int j = 0; j < 4; ++j) {
                float v = 0.f;
                if ((k0 + kk) < kend) v = W[(size_t)(k0 + kk) * KO + col0 + cc + j];
                sW[kk][cc + j] = v;
            }
        }
        __syncthreads();
#pragma unroll 8
        for (int k = 0; k < 16; ++k) {
            float2 a = *reinterpret_cast<const float2*>(&sA[k][r0]);
            float4 w = *reinterpret_cast<const float4*>(&sW[k][c0]);
            acc[0][0] = fmaf(a.x, w.x, acc[0][0]); acc[0][1] = fmaf(a.x, w.y, acc[0][1]);
            acc[0][2] = fmaf(a.x, w.z, acc[0][2]); acc[0][3] = fmaf(a.x, w.w, acc[0][3]);
            acc[1][0] = fmaf(a.y, w.x, acc[1][0]); acc[1][1] = fmaf(a.y, w.y, acc[1][1]);
            acc[1][2] = fmaf(a.y, w.z, acc[1][2]); acc[1][3] = fmaf(a.y, w.w, acc[1][3]);
        }
        __syncthreads();
    }
#pragma unroll
    for (int ri = 0; ri < 2; ++ri) {
        int row = row0 + r0 + ri;
        if (row >= n) continue;
        *reinterpret_cast<float4*>(&partial[((size_t)z * n + row) * KO + col0 + c0]) =
            make_float4(acc[ri][0], acc[ri][1], acc[ri][2], acc[ri][3]);
    }
}

// sum partials over splits + bias (+relu), scatter into C[row*ldc + col_off + col]
template <int NS, bool RELU>
__global__ void head_reduce(const float* __restrict__ partial, const float* __restrict__ bias,
                            float* __restrict__ C, int n, int KO, int ldc, int col_off) {
    int j = blockIdx.x * blockDim.x + threadIdx.x;
    if (j >= n * KO) return;
    int row = j / KO, col = j % KO;
    float acc = bias[col];
#pragma unroll
    for (int s = 0; s < NS; ++s) acc += partial[((size_t)s * n + row) * KO + col];
    if (RELU) acc = fmaxf(acc, 0.f);
    C[(size_t)row * ldc + col_off + col] = acc;
}

// ---------------- Conv1d as implicit GEMM via MFMA (bf16), K-split ----------------
__global__ __launch_bounds__(256) void conv_mfma(const float* __restrict__ T,
                                                 const ushort* __restrict__ Kbf,
                                                 float* __restrict__ partial) {
    __shared__ ushort sA[64][40];
    __shared__ ushort sB[32][40];
    const int t = threadIdx.x;
    const int row0 = blockIdx.x * 64;
    const int split = blockIdx.y;
    const int kbeg = split * CONV_KCHUNK;
    const int kend = min(6000, kbeg + CONV_KCHUNK);
    const int wid = t >> 6, lane = t & 63;
    const int lrow = lane & 15, kgrp = lane >> 4;
    f32x4 acc0 = (f32x4)0.f, acc1 = (f32x4)0.f;
    for (int k0 = kbeg; k0 < kend; k0 += 32) {
        {   // stage A (64 rows x 32 k): load fp32 T, convert to bf16 (kb multiple of 8)
            int rr = t >> 2, kq = t & 3;
            int grow = row0 + rr;                 // < 6144 always
            int b = grow / 12, h = grow % 12;
            int kb = k0 + kq * 8;
            int i = kb >> 3;
            const float* tp = &T[(size_t)b * 14250 + (size_t)i * 19 + h];
            ushort u[8];
#pragma unroll
            for (int j = 0; j < 8; ++j)
                u[j] = (kb + j < kend) ? f2bs(tp[j]) : (ushort)0;
            uint4 v;
            v.x = (uint)u[0] | ((uint)u[1] << 16);
            v.y = (uint)u[2] | ((uint)u[3] << 16);
            v.z = (uint)u[4] | ((uint)u[5] << 16);
            v.w = (uint)u[6] | ((uint)u[7] << 16);
            *reinterpret_cast<uint4*>(&sA[rr][kq * 8]) = v;
        }
        if (t < 128) {   // stage B (32 outs x 32 k) from padded Kbf
            int o = t >> 2, kq = t & 3;
            uint4 v = *reinterpret_cast<const uint4*>(&Kbf[(size_t)o * 6016 + k0 + kq * 8]);
            *reinterpret_cast<uint4*>(&sB[o][kq * 8]) = v;
        }
        __syncthreads();
        s16x8 a0 = *reinterpret_cast<const s16x8*>(&sA[wid * 16 + lrow][kgrp * 8]);
        s16x8 b0 = *reinterpret_cast<const s16x8*>(&sB[lrow][kgrp * 8]);
        s16x8 b1 = *reinterpret_cast<const s16x8*>(&sB[16 + lrow][kgrp * 8]);
        acc0 = __builtin_amdgcn_mfma_f32_16x16x32_bf16(a0, b0, acc0, 0, 0, 0);
        acc1 = __builtin_amdgcn_mfma_f32_16x16x32_bf16(a0, b1, acc1, 0, 0, 0);
        __syncthreads();
    }
#pragma unroll
    for (int r = 0; r < 4; ++r) {
        int row = row0 + wid * 16 + kgrp * 4 + r;   // C/D: row=(lane>>4)*4+reg, col=lane&15
        int b = row / 12, h = row % 12;
        partial[(((size_t)split * NBATCH + b) * 32 + lrow) * 12 + h] = acc0[r];
        partial[(((size_t)split * NBATCH + b) * 32 + (16 + lrow)) * 12 + h] = acc1[r];
    }
}

__global__ void conv_reduce(const float* __restrict__ partial, const float* __restrict__ bxt,
                            float* __restrict__ convb) {
    int j = blockIdx.x * blockDim.x + threadIdx.x;
    if (j >= NBATCH * 384) return;
    int b = j / 384, rem = j % 384;
    int o = rem / 12, h = rem % 12;
    float acc = bxt[o];
#pragma unroll
    for (int s = 0; s < CONV_KSPLIT; ++s)
        acc += partial[(((size_t)s * NBATCH + b) * 32 + o) * 12 + h];
    convb[j] = acc;
}

// ---------------- final [512,512] @ [512,1] ----------------
__global__ void final_out(const float* __restrict__ f2, const float* __restrict__ Wo,
                          const float* __restrict__ bo, float* __restrict__ out) {
    int row = blockIdx.x * (blockDim.x / 64) + (threadIdx.x / 64);
    int lane = threadIdx.x & 63;
    if (row >= NBATCH) return;
    float acc = 0.f;
    for (int k = lane; k < 512; k += 64) acc = fmaf(f2[(size_t)row * 512 + k], Wo[k], acc);
#pragma unroll
    for (int off = 32; off > 0; off >>= 1) acc += __shfl_down(acc, off);
    if (lane == 0) out[row] = acc + bo[0];
}

extern "C" void kernel_launch(void* const* d_in, const int* in_sizes, int n_in,
                              void* d_out, int out_size, void* d_ws, size_t ws_size,
                              hipStream_t stream) {
    (void)in_sizes; (void)n_in; (void)out_size; (void)ws_size;
    const float* x     = (const float*)d_in[0];
    const int*   ei    = (const int*)d_in[1];
    const int*   batch = (const int*)d_in[2];
    const float* T     = (const float*)d_in[3];
    const float* W1 = (const float*)d_in[4];   const float* b1 = (const float*)d_in[5];
    const float* W2 = (const float*)d_in[6];   const float* b2 = (const float*)d_in[7];
    const float* W3 = (const float*)d_in[8];   const float* b3 = (const float*)d_in[9];
    const float* Wg1 = (const float*)d_in[10]; const float* bg1 = (const float*)d_in[11];
    const float* Wg2 = (const float*)d_in[12]; const float* bg2 = (const float*)d_in[13];
    const float* Kxt = (const float*)d_in[14]; const float* bxt = (const float*)d_in[15];
    const float* Wxt = (const float*)d_in[16]; const float* bxt2 = (const float*)d_in[17];
    const float* Wf1 = (const float*)d_in[18]; const float* bf1 = (const float*)d_in[19];
    const float* Wf2 = (const float*)d_in[20]; const float* bf2 = (const float*)d_in[21];
    const float* Wo = (const float*)d_in[22];  const float* bo = (const float*)d_in[23];
    const int* src = ei;
    const int* dst = ei + N_EDGESC;

    char* ws = (char*)d_ws;
    size_t off = 0;
    auto alloc = [&](size_t bytes) -> void* {
        void* p = ws + off;
        off += (bytes + 255) & ~(size_t)255;
        return p;
    };
    int*   deg      = (int*)alloc((size_t)N_NODESC * 4);
    float* dinv     = (float*)alloc((size_t)N_NODESC * 4);
    int*   row_ptr  = (int*)alloc((size_t)(N_NODESC + 1) * 4);
    int*   fillc    = (int*)alloc((size_t)N_NODESC * 4);
    int*   csr_src  = (int*)alloc((size_t)N_EDGESC * 4);
    int*   csums    = (int*)alloc((size_t)4096 * 4);
    float* g0       = (float*)alloc((size_t)NBATCH * 312 * 4);
    float* g1       = (float*)alloc((size_t)NBATCH * 1024 * 4);
    float* convb    = (float*)alloc((size_t)NBATCH * 384 * 4);
    float* xc       = (float*)alloc((size_t)NBATCH * 256 * 4);
    float* f1       = (float*)alloc((size_t)NBATCH * 1024 * 4);
    float* f2       = (float*)alloc((size_t)NBATCH * 512 * 4);
    float* cpart    = (float*)alloc((size_t)CONV_KSPLIT * NBATCH * 32 * 12 * 4);
    float* hpart    = (float*)alloc((size_t)4 * NBATCH * 1024 * 4);   // 8MB: max NS*n*KO
    ushort* xbf     = (ushort*)alloc((size_t)N_NODESC * 80 * 2);   // x' (80) -> later h1' (80)
    ushort* aggbuf  = (ushort*)alloc((size_t)N_NODESC * 160 * 2);  // agg1/2 (80), agg3 (160)
    ushort* hbuf    = (ushort*)alloc((size_t)N_NODESC * 160 * 2);  // h2' (160)
    ushort* Wt1     = (ushort*)alloc((size_t)78 * 80 * 2);
    ushort* Wt2     = (ushort*)alloc((size_t)156 * 80 * 2);
    ushort* Wt3     = (ushort*)alloc((size_t)312 * 160 * 2);
    ushort* Kbf     = (ushort*)alloc((size_t)32 * 6016 * 2);
    float* out      = (float*)d_out;

    const int TPB = 256;

    // ---- graph structure ----
    zero_ints<<<divup(N_NODESC, TPB), TPB, 0, stream>>>(deg, N_NODESC);
    count_deg<<<divup(N_EDGESC, TPB), TPB, 0, stream>>>(dst, deg, N_EDGESC);
    compute_dinv<<<divup(N_NODESC, TPB), TPB, 0, stream>>>(deg, dinv, N_NODESC);
    int nchunks = divup(N_NODESC, SCAN_CHUNK);
    scan_chunks<<<nchunks, 256, 0, stream>>>(deg, row_ptr, csums, N_NODESC);
    scan_sums<<<1, 64, 0, stream>>>(csums, nchunks);
    finalize_rowptr<<<divup(N_NODESC, TPB), TPB, 0, stream>>>(row_ptr, csums, fillc, N_NODESC, N_EDGESC);
    fill_csr<<<divup(N_EDGESC, TPB), TPB, 0, stream>>>(src, dst, fillc, csr_src, N_EDGESC);

    // ---- bf16 conversions (x folded with dinv) ----
    convert_x_bf16<<<divup(N_NODESC * 80, TPB), TPB, 0, stream>>>(x, dinv, xbf, N_NODESC, 78, 80);
    transpose_w_bf16<<<divup(78 * 80, TPB), TPB, 0, stream>>>(W1, Wt1, 78, 78, 80);
    transpose_w_bf16<<<divup(156 * 80, TPB), TPB, 0, stream>>>(W2, Wt2, 78, 156, 80);
    transpose_w_bf16<<<divup(312 * 160, TPB), TPB, 0, stream>>>(W3, Wt3, 156, 312, 160);
    convert_k_bf16<<<divup(32 * 6016, TPB), TPB, 0, stream>>>(Kxt, Kbf);

    // ---- GCN layer 1: agg(x') -> gemm(+bias+relu, *dinv) -> h1' (LD 80) ----
    gcn_gather_vec<80><<<divup(N_NODESC * 10, TPB), TPB, 0, stream>>>(
        xbf, row_ptr, csr_src, dinv, aggbuf, N_NODESC);
    gemm_mfma<78, 80, 78, 80, 2, true><<<divup(N_NODESC, 64) * 2, 256, 0, stream>>>(
        aggbuf, Wt1, b1, dinv, xbf, N_NODESC);   // h1' overwrites xbf

    // ---- GCN layer 2: agg(h1') -> gemm(*dinv) -> h2' (LD 160) ----
    gcn_gather_vec<80><<<divup(N_NODESC * 10, TPB), TPB, 0, stream>>>(
        xbf, row_ptr, csr_src, dinv, aggbuf, N_NODESC);
    gemm_mfma<78, 80, 156, 160, 3, true><<<divup(N_NODESC, 64) * 3, 256, 0, stream>>>(
        aggbuf, Wt2, b2, dinv, hbuf, N_NODESC);

    // ---- GCN layer 3: agg(h2') -> gemm + FUSED segment-max -> g0 (h3 never materialized) ----
    gcn_gather_vec<160><<<divup(N_NODESC * 20, TPB), TPB, 0, stream>>>(
        hbuf, row_ptr, csr_src, dinv, aggbuf, N_NODESC);
    zero_ints<<<divup(NBATCH * 312, TPB), TPB, 0, stream>>>((int*)g0, NBATCH * 312);
    gemm_mfma_segmax<<<divup(N_NODESC, 64) * 5, 256, 0, stream>>>(
        aggbuf, Wt3, b3, batch, (uint*)g0, N_NODESC);

    // ---- graph head: g1 = relu(g0 @ Wg1 + bg1) — 3 K-splits, 768 blocks ----
    gemm_head<312, 1024, 112><<<dim3(16, 16, 3), 256, 0, stream>>>(g0, Wg1, hpart, NBATCH);
    head_reduce<3, true><<<divup(NBATCH * 1024, TPB), TPB, 0, stream>>>(
        hpart, bg1, g1, NBATCH, 1024, 1024, 0);
    // xc[:, :128] = g1 @ Wg2 + bg2 — 16 K-splits, 512 blocks
    gemm_head<1024, 128, 64><<<dim3(16, 2, 16), 256, 0, stream>>>(g1, Wg2, hpart, NBATCH);
    head_reduce<16, false><<<divup(NBATCH * 128, TPB), TPB, 0, stream>>>(
        hpart, bg2, xc, NBATCH, 128, 256, 0);

    // ---- protein branch: implicit-GEMM conv via MFMA ----
    conv_mfma<<<dim3(6144 / 64, CONV_KSPLIT), 256, 0, stream>>>(T, Kbf, cpart);
    conv_reduce<<<divup(NBATCH * 384, TPB), TPB, 0, stream>>>(cpart, bxt, convb);
    // xc[:, 128:] = convb @ Wxt + bxt2 — 16 K-splits, 512 blocks
    gemm_head<384, 128, 24><<<dim3(16, 2, 16), 256, 0, stream>>>(convb, Wxt, hpart, NBATCH);
    head_reduce<16, false><<<divup(NBATCH * 128, TPB), TPB, 0, stream>>>(
        hpart, bxt2, xc, NBATCH, 128, 256, 128);

    // ---- fusion MLP: f1 — 4 K-splits, 1024 blocks; f2 — 8 K-splits, 1024 blocks ----
    gemm_head<256, 1024, 64><<<dim3(16, 16, 4), 256, 0, stream>>>(xc, Wf1, hpart, NBATCH);
    head_reduce<4, true><<<divup(NBATCH * 1024, TPB), TPB, 0, stream>>>(
        hpart, bf1, f1, NBATCH, 1024, 1024, 0);
    gemm_head<1024, 512, 128><<<dim3(16, 8, 8), 256, 0, stream>>>(f1, Wf2, hpart, NBATCH);
    head_reduce<8, true><<<divup(NBATCH * 512, TPB), TPB, 0, stream>>>(
        hpart, bf2, f2, NBATCH, 512, 512, 0);
    final_out<<<divup(NBATCH, 4), 256, 0, stream>>>(f2, Wo, bo, out);
}

// Round 16
// 383.385 us; speedup vs baseline: 1.4262x; 1.0152x over previous
//
#include <hip/hip_runtime.h>
#include <hip/hip_bf16.h>
#include <cstddef>
#include <cstdint>

#define N_NODESC 100000
#define N_EDGESC 500000
#define NBATCH   512
#define SCAN_CHUNK 1024
#define CONV_KSPLIT 16
#define CONV_KCHUNK 384    // multiple of 32 -> k-octets stay channel-aligned; last split ragged (240)

static inline int divup(int a, int b) { return (a + b - 1) / b; }

typedef __hip_bfloat16 bf16;
typedef short s16x8 __attribute__((ext_vector_type(8)));
typedef float f32x4 __attribute__((ext_vector_type(4)));

__device__ inline float b2f(ushort u) {
    union { uint i; float f; } c; c.i = (uint)u << 16; return c.f;
}
__device__ inline ushort f2bs(float v) {
    bf16 b = __float2bfloat16(v);
    return *reinterpret_cast<ushort*>(&b);
}
__device__ inline void unpack2(uint u, float& a, float& b) {
    union { uint i; float f; } lo, hi;
    lo.i = u << 16; hi.i = u & 0xffff0000u;
    a = lo.f; b = hi.f;
}

// ---------------- zero ints ----------------
__global__ void zero_ints(int* __restrict__ p, int n) {
    int i = blockIdx.x * blockDim.x + threadIdx.x;
    if (i < n) p[i] = 0;
}

// ---------------- degree / dinv ----------------
__global__ void count_deg(const int* __restrict__ dst, int* __restrict__ deg, int e) {
    int i = blockIdx.x * blockDim.x + threadIdx.x;
    if (i < e) atomicAdd(&deg[dst[i]], 1);
}

__global__ void compute_dinv(const int* __restrict__ deg, float* __restrict__ dinv, int n) {
    int i = blockIdx.x * blockDim.x + threadIdx.x;
    if (i < n) dinv[i] = 1.0f / sqrtf((float)deg[i] + 1.0f);
}

// ---------------- exclusive scan (3-phase) ----------------
__global__ void scan_chunks(const int* __restrict__ deg, int* __restrict__ out,
                            int* __restrict__ sums, int n) {
    __shared__ int sdata[256];
    int t = threadIdx.x;
    int base = blockIdx.x * SCAN_CHUNK;
    int v[4];
    int s = 0;
#pragma unroll
    for (int j = 0; j < 4; ++j) {
        int idx = base + t * 4 + j;
        v[j] = s;
        int d = (idx < n) ? deg[idx] : 0;
        s += d;
    }
    int x = s;
    sdata[t] = x;
    __syncthreads();
    for (int off = 1; off < 256; off <<= 1) {
        int y = (t >= off) ? sdata[t - off] : 0;
        __syncthreads();
        x += y;
        sdata[t] = x;
        __syncthreads();
    }
    int thread_excl = x - s;
    if (t == 255) sums[blockIdx.x] = x;
#pragma unroll
    for (int j = 0; j < 4; ++j) {
        int idx = base + t * 4 + j;
        if (idx < n) out[idx] = thread_excl + v[j];
    }
}

__global__ void scan_sums(int* sums, int nchunks) {
    if (threadIdx.x == 0 && blockIdx.x == 0) {
        int acc = 0;
        for (int i = 0; i < nchunks; ++i) { int v = sums[i]; sums[i] = acc; acc += v; }
    }
}

__global__ void finalize_rowptr(int* __restrict__ row_ptr, const int* __restrict__ sums,
                                int* __restrict__ fill, int n, int e) {
    int i = blockIdx.x * blockDim.x + threadIdx.x;
    if (i < n) {
        int v = row_ptr[i] + sums[i / SCAN_CHUNK];
        row_ptr[i] = v;
        fill[i] = v;
    }
    if (i == 0) row_ptr[n] = e;
}

__global__ void fill_csr(const int* __restrict__ src, const int* __restrict__ dst,
                         int* __restrict__ fill, int* __restrict__ csr_src, int e) {
    int i = blockIdx.x * blockDim.x + threadIdx.x;
    if (i < e) {
        int d = dst[i];
        int pos = atomicAdd(&fill[d], 1);
        csr_src[pos] = src[i];
    }
}

// ---------------- fp32 -> bf16 node features, scaled by dinv[node], padded stride ----------------
__global__ void convert_x_bf16(const float* __restrict__ x, const float* __restrict__ dinv,
                               ushort* __restrict__ xbf, int n, int ki, int ld) {
    int i = blockIdx.x * blockDim.x + threadIdx.x;
    int total = n * ld;
    if (i >= total) return;
    int node = i / ld, col = i % ld;
    xbf[i] = (col < ki) ? f2bs(x[(size_t)node * ki + col] * dinv[node]) : (ushort)0;
}

// ---------------- W[KI,KO] fp32 -> Wt[KO,LD] bf16 (transposed, zero-padded) ----------------
__global__ void transpose_w_bf16(const float* __restrict__ W, ushort* __restrict__ Wt,
                                 int ki, int ko, int ld) {
    int i = blockIdx.x * blockDim.x + threadIdx.x;
    int total = ko * ld;
    if (i >= total) return;
    int o = i / ld, k = i % ld;
    Wt[i] = (k < ki) ? f2bs(W[(size_t)k * ko + o]) : (ushort)0;
}

// ---------------- Kxt[32][6000] fp32 -> Kbf[32][6016] bf16 (zero-padded) ----------------
__global__ void convert_k_bf16(const float* __restrict__ Kxt, ushort* __restrict__ Kbf) {
    int i = blockIdx.x * blockDim.x + threadIdx.x;
    if (i >= 32 * 6016) return;
    int o = i / 6016, k = i % 6016;
    Kbf[i] = (k < 6000) ? f2bs(Kxt[(size_t)o * 6000 + k]) : (ushort)0;
}

// ---------------- vectorized GCN aggregation on dinv-prescaled features ----------------
template <int LD>
__global__ void gcn_gather_vec(const ushort* __restrict__ h, const int* __restrict__ row_ptr,
                               const int* __restrict__ csr_src, const float* __restrict__ dinv,
                               ushort* __restrict__ agg, int n) {
    constexpr int TPN = LD / 8;
    int gid = blockIdx.x * blockDim.x + threadIdx.x;
    int node = gid / TPN, oct = gid % TPN;
    if (node >= n) return;
    float dn = dinv[node];
    int e0 = row_ptr[node], e1 = row_ptr[node + 1];
    float acc[8];
    {   // self term: h'[node]
        uint4 v = *reinterpret_cast<const uint4*>(&h[(size_t)node * LD + oct * 8]);
        unpack2(v.x, acc[0], acc[1]);
        unpack2(v.y, acc[2], acc[3]);
        unpack2(v.z, acc[4], acc[5]);
        unpack2(v.w, acc[6], acc[7]);
    }
    for (int e = e0; e < e1; ++e) {
        int s = csr_src[e];
        uint4 v = *reinterpret_cast<const uint4*>(&h[(size_t)s * LD + oct * 8]);
        float a, b;
        unpack2(v.x, a, b); acc[0] += a; acc[1] += b;
        unpack2(v.y, a, b); acc[2] += a; acc[3] += b;
        unpack2(v.z, a, b); acc[4] += a; acc[5] += b;
        unpack2(v.w, a, b); acc[6] += a; acc[7] += b;
    }
    uint4 o;
    o.x = (uint)f2bs(acc[0] * dn) | ((uint)f2bs(acc[1] * dn) << 16);
    o.y = (uint)f2bs(acc[2] * dn) | ((uint)f2bs(acc[3] * dn) << 16);
    o.z = (uint)f2bs(acc[4] * dn) | ((uint)f2bs(acc[5] * dn) << 16);
    o.w = (uint)f2bs(acc[6] * dn) | ((uint)f2bs(acc[7] * dn) << 16);
    *reinterpret_cast<uint4*>(&agg[(size_t)node * LD + oct * 8]) = o;
}

// ---------------- bf16 MFMA GEMM: C = A @ Wt^T (+bias+relu)(*rowscale), bf16 out ----------------
template <int KI, int LDA, int KO, int LDC, int NBY, bool SCALEROW>
__global__ __launch_bounds__(256) void gemm_mfma(const ushort* __restrict__ A,
                                                 const ushort* __restrict__ Bt,
                                                 const float* __restrict__ bias,
                                                 const float* __restrict__ rowscale,
                                                 ushort* __restrict__ C, int n) {
    __shared__ ushort sA[64][40];
    __shared__ ushort sB[64][40];
    const int t = threadIdx.x;
    const int row0 = (blockIdx.x / NBY) * 64;
    const int col0 = (blockIdx.x % NBY) * 64;
    const int wid = t >> 6, lane = t & 63;
    const int wr = wid >> 1, wc = wid & 1;
    const int lrow = lane & 15;
    const int kgrp = lane >> 4;
    const int srr = t >> 2;      // staging row 0..63
    const int skq = t & 3;       // staging k-octet
    f32x4 acc[2][2];
#pragma unroll
    for (int i = 0; i < 2; ++i)
#pragma unroll
        for (int j = 0; j < 2; ++j) acc[i][j] = (f32x4)0.f;

    const int nk = (KI + 31) / 32;
    for (int ks = 0; ks < nk; ++ks) {
        const int kbase = ks * 32 + skq * 8;
        {   // stage A tile (64 rows x 32 k)
            int grow = row0 + srr;
            uint4 v = {0, 0, 0, 0};
            if (grow < n && kbase < LDA)
                v = *reinterpret_cast<const uint4*>(&A[(size_t)grow * LDA + kbase]);
            *reinterpret_cast<uint4*>(&sA[srr][skq * 8]) = v;
        }
        {   // stage B tile (64 cols x 32 k)
            int gcol = col0 + srr;
            uint4 v = {0, 0, 0, 0};
            if (gcol < KO && kbase < LDA)
                v = *reinterpret_cast<const uint4*>(&Bt[(size_t)gcol * LDA + kbase]);
            *reinterpret_cast<uint4*>(&sB[srr][skq * 8]) = v;
        }
        __syncthreads();
        s16x8 a0 = *reinterpret_cast<const s16x8*>(&sA[wr * 32 + lrow][kgrp * 8]);
        s16x8 a1 = *reinterpret_cast<const s16x8*>(&sA[wr * 32 + 16 + lrow][kgrp * 8]);
        s16x8 b0 = *reinterpret_cast<const s16x8*>(&sB[wc * 32 + lrow][kgrp * 8]);
        s16x8 b1 = *reinterpret_cast<const s16x8*>(&sB[wc * 32 + 16 + lrow][kgrp * 8]);
        acc[0][0] = __builtin_amdgcn_mfma_f32_16x16x32_bf16(a0, b0, acc[0][0], 0, 0, 0);
        acc[0][1] = __builtin_amdgcn_mfma_f32_16x16x32_bf16(a0, b1, acc[0][1], 0, 0, 0);
        acc[1][0] = __builtin_amdgcn_mfma_f32_16x16x32_bf16(a1, b0, acc[1][0], 0, 0, 0);
        acc[1][1] = __builtin_amdgcn_mfma_f32_16x16x32_bf16(a1, b1, acc[1][1], 0, 0, 0);
        __syncthreads();
    }
#pragma unroll
    for (int fr = 0; fr < 2; ++fr)
#pragma unroll
        for (int fc = 0; fc < 2; ++fc)
#pragma unroll
            for (int r = 0; r < 4; ++r) {
                int row = row0 + wr * 32 + fr * 16 + kgrp * 4 + r;
                int col = col0 + wc * 32 + fc * 16 + lrow;
                if (row < n && col < LDC) {
                    float v = acc[fr][fc][r];
                    ushort o = 0;
                    if (col < KO) {
                        v = fmaxf(v + bias[col], 0.f);
                        if (SCALEROW) v *= rowscale[row];
                        o = f2bs(v);
                    }
                    C[(size_t)row * LDC + col] = o;
                }
            }
}

// ---------------- layer-3 MFMA GEMM with FUSED segment-max pool ----------------
// XCD-chunked block remap: the 5 column-blocks of a row-group share bid%8 -> same XCD L2,
// so the A row-tile is fetched from HBM once and re-served from that XCD's L2.
__global__ __launch_bounds__(256) void gemm_mfma_segmax(const ushort* __restrict__ A,
                                                        const ushort* __restrict__ Bt,
                                                        const float* __restrict__ bias,
                                                        const int* __restrict__ batch,
                                                        uint* __restrict__ g0u, int n) {
    constexpr int KI = 156, LDA = 160, KO = 312, NBY = 5;
    constexpr int NRG = (N_NODESC + 63) / 64;        // 1563 row-groups
    constexpr int Q = NRG / 8, R = NRG % 8;          // chunks of 196 (xcd<R) or 195
    __shared__ ushort sA[64][40];
    __shared__ ushort sB[64][40];
    __shared__ ushort sC[64][66];
    __shared__ int sbatch[64];
    const int bid = blockIdx.x;
    const int xcd = bid & 7;
    const int idx = bid >> 3;                        // 0..979
    const int chunk = Q + (xcd < R ? 1 : 0);
    const int rgl = idx / NBY;
    if (rgl >= chunk) return;                        // uniform idle block (pre-barrier)
    const int rg = xcd * Q + min(xcd, R) + rgl;
    const int row0 = rg * 64;
    const int col0 = (idx % NBY) * 64;
    const int t = threadIdx.x;
    const int wid = t >> 6, lane = t & 63;
    const int wr = wid >> 1, wc = wid & 1;
    const int lrow = lane & 15;
    const int kgrp = lane >> 4;
    const int srr = t >> 2;
    const int skq = t & 3;
    if (t < 64) sbatch[t] = (row0 + t < n) ? batch[row0 + t] : -1;
    f32x4 acc[2][2];
#pragma unroll
    for (int i = 0; i < 2; ++i)
#pragma unroll
        for (int j = 0; j < 2; ++j) acc[i][j] = (f32x4)0.f;

    const int nk = (KI + 31) / 32;
    for (int ks = 0; ks < nk; ++ks) {
        const int kbase = ks * 32 + skq * 8;
        {
            int grow = row0 + srr;
            uint4 v = {0, 0, 0, 0};
            if (grow < n && kbase < LDA)
                v = *reinterpret_cast<const uint4*>(&A[(size_t)grow * LDA + kbase]);
            *reinterpret_cast<uint4*>(&sA[srr][skq * 8]) = v;
        }
        {
            int gcol = col0 + srr;
            uint4 v = {0, 0, 0, 0};
            if (gcol < KO && kbase < LDA)
                v = *reinterpret_cast<const uint4*>(&Bt[(size_t)gcol * LDA + kbase]);
            *reinterpret_cast<uint4*>(&sB[srr][skq * 8]) = v;
        }
        __syncthreads();
        s16x8 a0 = *reinterpret_cast<const s16x8*>(&sA[wr * 32 + lrow][kgrp * 8]);
        s16x8 a1 = *reinterpret_cast<const s16x8*>(&sA[wr * 32 + 16 + lrow][kgrp * 8]);
        s16x8 b0 = *reinterpret_cast<const s16x8*>(&sB[wc * 32 + lrow][kgrp * 8]);
        s16x8 b1 = *reinterpret_cast<const s16x8*>(&sB[wc * 32 + 16 + lrow][kgrp * 8]);
        acc[0][0] = __builtin_amdgcn_mfma_f32_16x16x32_bf16(a0, b0, acc[0][0], 0, 0, 0);
        acc[0][1] = __builtin_amdgcn_mfma_f32_16x16x32_bf16(a0, b1, acc[0][1], 0, 0, 0);
        acc[1][0] = __builtin_amdgcn_mfma_f32_16x16x32_bf16(a1, b0, acc[1][0], 0, 0, 0);
        acc[1][1] = __builtin_amdgcn_mfma_f32_16x16x32_bf16(a1, b1, acc[1][1], 0, 0, 0);
        __syncthreads();
    }
#pragma unroll
    for (int fr = 0; fr < 2; ++fr)
#pragma unroll
        for (int fc = 0; fc < 2; ++fc)
#pragma unroll
            for (int r = 0; r < 4; ++r) {
                int lr = wr * 32 + fr * 16 + kgrp * 4 + r;
                int lc = wc * 32 + fc * 16 + lrow;
                int gcol = col0 + lc;
                ushort o = 0;
                if (gcol < KO) o = f2bs(fmaxf(acc[fr][fc][r] + bias[gcol], 0.f));
                sC[lr][lc] = o;
            }
    __syncthreads();
    {
        int col = t & 63, q = t >> 6;
        int gcol = col0 + col;
        if (gcol < KO) {
            int base = q * 16;
            int cur = sbatch[base];
            float m = 0.f;
#pragma unroll 4
            for (int i = 0; i < 16; ++i) {
                int b = sbatch[base + i];
                if (b != cur) {
                    if (cur >= 0) atomicMax(&g0u[(size_t)cur * KO + gcol], __float_as_uint(m));
                    m = 0.f;
                    cur = b;
                }
                m = fmaxf(m, b2f(sC[base + i][col]));
            }
            if (cur >= 0) atomicMax(&g0u[(size_t)cur * KO + gcol], __float_as_uint(m));
        }
    }
}

// ---------------- head GEMM: K-split, 32x64 tile, fp32 partials ----------------
template <int KI, int KO, int KS>
__global__ __launch_bounds__(256) void gemm_head(const float* __restrict__ A,
                                                 const float* __restrict__ W,
                                                 float* __restrict__ partial, int n) {
    __shared__ float sA[16][34];
    __shared__ float sW[16][68];
    const int t = threadIdx.x;
    const int row0 = blockIdx.x * 32;
    const int col0 = blockIdx.y * 64;
    const int z = blockIdx.z;
    const int kbeg = z * KS;
    const int kend = min(KI, kbeg + KS);
    const int r0 = (t >> 4) * 2;   // 0..30 (even)
    const int c0 = (t & 15) * 4;   // 0..60 (quad)
    float acc[2][4] = {};
    for (int k0 = kbeg; k0 < kend; k0 += 16) {
        {   // stage A: 32 rows x 16 k
            int row = t >> 3, kk = (t & 7) * 2;
            int grow = row0 + row;
#pragma unroll
            for (int j = 0; j < 2; ++j) {
                float v = 0.f;
                if (grow < n && (k0 + kk + j) < kend) v = A[(size_t)grow * KI + k0 + kk + j];
                sA[kk + j][row] = v;
            }
        }
        {   // stage W: 16 k x 64 cols
            int kk = t >> 4, cc = (t & 15) * 4;
#pragma unroll
            for (int j = 0; j < 4; ++j) {
                float v = 0.f;
                if ((k0 + kk) < kend) v = W[(size_t)(k0 + kk) * KO + col0 + cc + j];
                sW[kk][cc + j] = v;
            }
        }
        __syncthreads();
#pragma unroll 8
        for (int k = 0; k < 16; ++k) {
            float2 a = *reinterpret_cast<const float2*>(&sA[k][r0]);
            float4 w = *reinterpret_cast<const float4*>(&sW[k][c0]);
            acc[0][0] = fmaf(a.x, w.x, acc[0][0]); acc[0][1] = fmaf(a.x, w.y, acc[0][1]);
            acc[0][2] = fmaf(a.x, w.z, acc[0][2]); acc[0][3] = fmaf(a.x, w.w, acc[0][3]);
            acc[1][0] = fmaf(a.y, w.x, acc[1][0]); acc[1][1] = fmaf(a.y, w.y, acc[1][1]);
            acc[1][2] = fmaf(a.y, w.z, acc[1][2]); acc[1][3] = fmaf(a.y, w.w, acc[1][3]);
        }
        __syncthreads();
    }
#pragma unroll
    for (int ri = 0; ri < 2; ++ri) {
        int row = row0 + r0 + ri;
        if (row >= n) continue;
        *reinterpret_cast<float4*>(&partial[((size_t)z * n + row) * KO + col0 + c0]) =
            make_float4(acc[ri][0], acc[ri][1], acc[ri][2], acc[ri][3]);
    }
}

// sum partials over splits + bias (+relu), scatter into C[row*ldc + col_off + col]
template <int NS, bool RELU>
__global__ void head_reduce(const float* __restrict__ partial, const float* __restrict__ bias,
                            float* __restrict__ C, int n, int KO, int ldc, int col_off) {
    int j = blockIdx.x * blockDim.x + threadIdx.x;
    if (j >= n * KO) return;
    int row = j / KO, col = j % KO;
    float acc = bias[col];
#pragma unroll
    for (int s = 0; s < NS; ++s) acc += partial[((size_t)s * n + row) * KO + col];
    if (RELU) acc = fmaxf(acc, 0.f);
    C[(size_t)row * ldc + col_off + col] = acc;
}

// ---------------- Conv1d as implicit GEMM via MFMA (bf16), K-split ----------------
__global__ __launch_bounds__(256) void conv_mfma(const float* __restrict__ T,
                                                 const ushort* __restrict__ Kbf,
                                                 float* __restrict__ partial) {
    __shared__ ushort sA[64][40];
    __shared__ ushort sB[32][40];
    const int t = threadIdx.x;
    const int row0 = blockIdx.x * 64;
    const int split = blockIdx.y;
    const int kbeg = split * CONV_KCHUNK;
    const int kend = min(6000, kbeg + CONV_KCHUNK);
    const int wid = t >> 6, lane = t & 63;
    const int lrow = lane & 15, kgrp = lane >> 4;
    f32x4 acc0 = (f32x4)0.f, acc1 = (f32x4)0.f;
    for (int k0 = kbeg; k0 < kend; k0 += 32) {
        {   // stage A (64 rows x 32 k): load fp32 T, convert to bf16 (kb multiple of 8)
            int rr = t >> 2, kq = t & 3;
            int grow = row0 + rr;                 // < 6144 always
            int b = grow / 12, h = grow % 12;
            int kb = k0 + kq * 8;
            int i = kb >> 3;
            const float* tp = &T[(size_t)b * 14250 + (size_t)i * 19 + h];
            ushort u[8];
#pragma unroll
            for (int j = 0; j < 8; ++j)
                u[j] = (kb + j < kend) ? f2bs(tp[j]) : (ushort)0;
            uint4 v;
            v.x = (uint)u[0] | ((uint)u[1] << 16);
            v.y = (uint)u[2] | ((uint)u[3] << 16);
            v.z = (uint)u[4] | ((uint)u[5] << 16);
            v.w = (uint)u[6] | ((uint)u[7] << 16);
            *reinterpret_cast<uint4*>(&sA[rr][kq * 8]) = v;
        }
        if (t < 128) {   // stage B (32 outs x 32 k) from padded Kbf
            int o = t >> 2, kq = t & 3;
            uint4 v = *reinterpret_cast<const uint4*>(&Kbf[(size_t)o * 6016 + k0 + kq * 8]);
            *reinterpret_cast<uint4*>(&sB[o][kq * 8]) = v;
        }
        __syncthreads();
        s16x8 a0 = *reinterpret_cast<const s16x8*>(&sA[wid * 16 + lrow][kgrp * 8]);
        s16x8 b0 = *reinterpret_cast<const s16x8*>(&sB[lrow][kgrp * 8]);
        s16x8 b1 = *reinterpret_cast<const s16x8*>(&sB[16 + lrow][kgrp * 8]);
        acc0 = __builtin_amdgcn_mfma_f32_16x16x32_bf16(a0, b0, acc0, 0, 0, 0);
        acc1 = __builtin_amdgcn_mfma_f32_16x16x32_bf16(a0, b1, acc1, 0, 0, 0);
        __syncthreads();
    }
#pragma unroll
    for (int r = 0; r < 4; ++r) {
        int row = row0 + wid * 16 + kgrp * 4 + r;   // C/D: row=(lane>>4)*4+reg, col=lane&15
        int b = row / 12, h = row % 12;
        partial[(((size_t)split * NBATCH + b) * 32 + lrow) * 12 + h] = acc0[r];
        partial[(((size_t)split * NBATCH + b) * 32 + (16 + lrow)) * 12 + h] = acc1[r];
    }
}

__global__ void conv_reduce(const float* __restrict__ partial, const float* __restrict__ bxt,
                            float* __restrict__ convb) {
    int j = blockIdx.x * blockDim.x + threadIdx.x;
    if (j >= NBATCH * 384) return;
    int b = j / 384, rem = j % 384;
    int o = rem / 12, h = rem % 12;
    float acc = bxt[o];
#pragma unroll
    for (int s = 0; s < CONV_KSPLIT; ++s)
        acc += partial[(((size_t)s * NBATCH + b) * 32 + o) * 12 + h];
    convb[j] = acc;
}

// ---------------- final [512,512] @ [512,1] ----------------
__global__ void final_out(const float* __restrict__ f2, const float* __restrict__ Wo,
                          const float* __restrict__ bo, float* __restrict__ out) {
    int row = blockIdx.x * (blockDim.x / 64) + (threadIdx.x / 64);
    int lane = threadIdx.x & 63;
    if (row >= NBATCH) return;
    float acc = 0.f;
    for (int k = lane; k < 512; k += 64) acc = fmaf(f2[(size_t)row * 512 + k], Wo[k], acc);
#pragma unroll
    for (int off = 32; off > 0; off >>= 1) acc += __shfl_down(acc, off);
    if (lane == 0) out[row] = acc + bo[0];
}

extern "C" void kernel_launch(void* const* d_in, const int* in_sizes, int n_in,
                              void* d_out, int out_size, void* d_ws, size_t ws_size,
                              hipStream_t stream) {
    (void)in_sizes; (void)n_in; (void)out_size; (void)ws_size;
    const float* x     = (const float*)d_in[0];
    const int*   ei    = (const int*)d_in[1];
    const int*   batch = (const int*)d_in[2];
    const float* T     = (const float*)d_in[3];
    const float* W1 = (const float*)d_in[4];   const float* b1 = (const float*)d_in[5];
    const float* W2 = (const float*)d_in[6];   const float* b2 = (const float*)d_in[7];
    const float* W3 = (const float*)d_in[8];   const float* b3 = (const float*)d_in[9];
    const float* Wg1 = (const float*)d_in[10]; const float* bg1 = (const float*)d_in[11];
    const float* Wg2 = (const float*)d_in[12]; const float* bg2 = (const float*)d_in[13];
    const float* Kxt = (const float*)d_in[14]; const float* bxt = (const float*)d_in[15];
    const float* Wxt = (const float*)d_in[16]; const float* bxt2 = (const float*)d_in[17];
    const float* Wf1 = (const float*)d_in[18]; const float* bf1 = (const float*)d_in[19];
    const float* Wf2 = (const float*)d_in[20]; const float* bf2 = (const float*)d_in[21];
    const float* Wo = (const float*)d_in[22];  const float* bo = (const float*)d_in[23];
    const int* src = ei;
    const int* dst = ei + N_EDGESC;

    char* ws = (char*)d_ws;
    size_t off = 0;
    auto alloc = [&](size_t bytes) -> void* {
        void* p = ws + off;
        off += (bytes + 255) & ~(size_t)255;
        return p;
    };
    int*   deg      = (int*)alloc((size_t)N_NODESC * 4);
    float* dinv     = (float*)alloc((size_t)N_NODESC * 4);
    int*   row_ptr  = (int*)alloc((size_t)(N_NODESC + 1) * 4);
    int*   fillc    = (int*)alloc((size_t)N_NODESC * 4);
    int*   csr_src  = (int*)alloc((size_t)N_EDGESC * 4);
    int*   csums    = (int*)alloc((size_t)4096 * 4);
    float* g0       = (float*)alloc((size_t)NBATCH * 312 * 4);
    float* g1       = (float*)alloc((size_t)NBATCH * 1024 * 4);
    float* convb    = (float*)alloc((size_t)NBATCH * 384 * 4);
    float* xc       = (float*)alloc((size_t)NBATCH * 256 * 4);
    float* f1       = (float*)alloc((size_t)NBATCH * 1024 * 4);
    float* f2       = (float*)alloc((size_t)NBATCH * 512 * 4);
    float* cpart    = (float*)alloc((size_t)CONV_KSPLIT * NBATCH * 32 * 12 * 4);
    float* hpart    = (float*)alloc((size_t)4 * NBATCH * 1024 * 4);   // 8MB: max NS*n*KO
    ushort* xbf     = (ushort*)alloc((size_t)N_NODESC * 80 * 2);   // x' (80) -> later h1' (80)
    ushort* aggbuf  = (ushort*)alloc((size_t)N_NODESC * 160 * 2);  // agg1/2 (80), agg3 (160)
    ushort* hbuf    = (ushort*)alloc((size_t)N_NODESC * 160 * 2);  // h2' (160)
    ushort* Wt1     = (ushort*)alloc((size_t)78 * 80 * 2);
    ushort* Wt2     = (ushort*)alloc((size_t)156 * 80 * 2);
    ushort* Wt3     = (ushort*)alloc((size_t)312 * 160 * 2);
    ushort* Kbf     = (ushort*)alloc((size_t)32 * 6016 * 2);
    float* out      = (float*)d_out;

    const int TPB = 256;

    // ---- graph structure ----
    zero_ints<<<divup(N_NODESC, TPB), TPB, 0, stream>>>(deg, N_NODESC);
    count_deg<<<divup(N_EDGESC, TPB), TPB, 0, stream>>>(dst, deg, N_EDGESC);
    compute_dinv<<<divup(N_NODESC, TPB), TPB, 0, stream>>>(deg, dinv, N_NODESC);
    int nchunks = divup(N_NODESC, SCAN_CHUNK);
    scan_chunks<<<nchunks, 256, 0, stream>>>(deg, row_ptr, csums, N_NODESC);
    scan_sums<<<1, 64, 0, stream>>>(csums, nchunks);
    finalize_rowptr<<<divup(N_NODESC, TPB), TPB, 0, stream>>>(row_ptr, csums, fillc, N_NODESC, N_EDGESC);
    fill_csr<<<divup(N_EDGESC, TPB), TPB, 0, stream>>>(src, dst, fillc, csr_src, N_EDGESC);

    // ---- bf16 conversions (x folded with dinv) ----
    convert_x_bf16<<<divup(N_NODESC * 80, TPB), TPB, 0, stream>>>(x, dinv, xbf, N_NODESC, 78, 80);
    transpose_w_bf16<<<divup(78 * 80, TPB), TPB, 0, stream>>>(W1, Wt1, 78, 78, 80);
    transpose_w_bf16<<<divup(156 * 80, TPB), TPB, 0, stream>>>(W2, Wt2, 78, 156, 80);
    transpose_w_bf16<<<divup(312 * 160, TPB), TPB, 0, stream>>>(W3, Wt3, 156, 312, 160);
    convert_k_bf16<<<divup(32 * 6016, TPB), TPB, 0, stream>>>(Kxt, Kbf);

    // ---- GCN layer 1: agg(x') -> gemm(+bias+relu, *dinv) -> h1' (LD 80) ----
    gcn_gather_vec<80><<<divup(N_NODESC * 10, TPB), TPB, 0, stream>>>(
        xbf, row_ptr, csr_src, dinv, aggbuf, N_NODESC);
    gemm_mfma<78, 80, 78, 80, 2, true><<<divup(N_NODESC, 64) * 2, 256, 0, stream>>>(
        aggbuf, Wt1, b1, dinv, xbf, N_NODESC);   // h1' overwrites xbf

    // ---- GCN layer 2: agg(h1') -> gemm(*dinv) -> h2' (LD 160) ----
    gcn_gather_vec<80><<<divup(N_NODESC * 10, TPB), TPB, 0, stream>>>(
        xbf, row_ptr, csr_src, dinv, aggbuf, N_NODESC);
    gemm_mfma<78, 80, 156, 160, 3, true><<<divup(N_NODESC, 64) * 3, 256, 0, stream>>>(
        aggbuf, Wt2, b2, dinv, hbuf, N_NODESC);

    // ---- GCN layer 3: agg(h2') -> gemm + FUSED segment-max (XCD-chunked grid) ----
    gcn_gather_vec<160><<<divup(N_NODESC * 20, TPB), TPB, 0, stream>>>(
        hbuf, row_ptr, csr_src, dinv, aggbuf, N_NODESC);
    zero_ints<<<divup(NBATCH * 312, TPB), TPB, 0, stream>>>((int*)g0, NBATCH * 312);
    gemm_mfma_segmax<<<8 * 196 * 5, 256, 0, stream>>>(
        aggbuf, Wt3, b3, batch, (uint*)g0, N_NODESC);

    // ---- graph head: g1 = relu(g0 @ Wg1 + bg1) — 3 K-splits, 768 blocks ----
    gemm_head<312, 1024, 112><<<dim3(16, 16, 3), 256, 0, stream>>>(g0, Wg1, hpart, NBATCH);
    head_reduce<3, true><<<divup(NBATCH * 1024, TPB), TPB, 0, stream>>>(
        hpart, bg1, g1, NBATCH, 1024, 1024, 0);
    // xc[:, :128] = g1 @ Wg2 + bg2 — 16 K-splits, 512 blocks
    gemm_head<1024, 128, 64><<<dim3(16, 2, 16), 256, 0, stream>>>(g1, Wg2, hpart, NBATCH);
    head_reduce<16, false><<<divup(NBATCH * 128, TPB), TPB, 0, stream>>>(
        hpart, bg2, xc, NBATCH, 128, 256, 0);

    // ---- protein branch: implicit-GEMM conv via MFMA ----
    conv_mfma<<<dim3(6144 / 64, CONV_KSPLIT), 256, 0, stream>>>(T, Kbf, cpart);
    conv_reduce<<<divup(NBATCH * 384, TPB), TPB, 0, stream>>>(cpart, bxt, convb);
    // xc[:, 128:] = convb @ Wxt + bxt2 — 16 K-splits, 512 blocks
    gemm_head<384, 128, 24><<<dim3(16, 2, 16), 256, 0, stream>>>(convb, Wxt, hpart, NBATCH);
    head_reduce<16, false><<<divup(NBATCH * 128, TPB), TPB, 0, stream>>>(
        hpart, bxt2, xc, NBATCH, 128, 256, 128);

    // ---- fusion MLP: f1 — 4 K-splits, 1024 blocks; f2 — 8 K-splits, 1024 blocks ----
    gemm_head<256, 1024, 64><<<dim3(16, 16, 4), 256, 0, stream>>>(xc, Wf1, hpart, NBATCH);
    head_reduce<4, true><<<divup(NBATCH * 1024, TPB), TPB, 0, stream>>>(
        hpart, bf1, f1, NBATCH, 1024, 1024, 0);
    gemm_head<1024, 512, 128><<<dim3(16, 8, 8), 256, 0, stream>>>(f1, Wf2, hpart, NBATCH);
    head_reduce<8, true><<<divup(NBATCH * 512, TPB), TPB, 0, stream>>>(
        hpart, bf2, f2, NBATCH, 512, 512, 0);
    final_out<<<divup(NBATCH, 4), 256, 0, stream>>>(f2, Wo, bo, out);
}